// Round 1
// baseline (841.742 us; speedup 1.0000x reference)
//
#include <hip/hip_runtime.h>
#include <hip/hip_bf16.h>
#include <math.h>

// ---------------------------------------------------------------------------
// GAT 2-layer forward, fp32 throughout.
// Pipeline:
//   1. CSR build by dst (counts -> scan -> scatter), graph shared by both layers
//   2. h1 = x @ W1            (LDS-tiled fp32 GEMM, W resident in LDS)
//   3. a_s1/a_d1 = <h1, att>  (wave per (node, head))
//   4. aggregate1: per-dst-node gather softmax + weighted sum, +b1, elu -> x2
//   5. h2 = x2 @ W2
//   6. a_s2/a_d2
//   7. aggregate2 -> d_out (+b2, head mean)
// ---------------------------------------------------------------------------

// ------------------------- CSR build -------------------------

__global__ void init_kernel(int* __restrict__ counts, int* __restrict__ fill, int N) {
    int i = blockIdx.x * blockDim.x + threadIdx.x;
    if (i < N) { counts[i] = 1; fill[i] = 0; }  // counts starts at 1: self-loop
}

__global__ void hist_kernel(const int* __restrict__ dst, int* __restrict__ counts, int E) {
    int i = blockIdx.x * blockDim.x + threadIdx.x;
    if (i < E) atomicAdd(&counts[dst[i]], 1);
}

__global__ void scan_a_kernel(const int* __restrict__ counts, int* __restrict__ bsum, int N) {
    __shared__ int sd[256];
    int t = threadIdx.x;
    int i = blockIdx.x * 256 + t;
    sd[t] = (i < N) ? counts[i] : 0;
    __syncthreads();
    for (int o = 128; o > 0; o >>= 1) {
        if (t < o) sd[t] += sd[t + o];
        __syncthreads();
    }
    if (t == 0) bsum[blockIdx.x] = sd[0];
}

__launch_bounds__(1024)
__global__ void scan_b_kernel(const int* __restrict__ bsum, int* __restrict__ boff,
                              int* __restrict__ rowptr, int NB, int N) {
    __shared__ int sd[1024];
    int t = threadIdx.x;
    int v = (t < NB) ? bsum[t] : 0;
    sd[t] = v;
    __syncthreads();
    for (int o = 1; o < 1024; o <<= 1) {
        int x = (t >= o) ? sd[t - o] : 0;
        __syncthreads();
        sd[t] += x;
        __syncthreads();
    }
    if (t < NB) boff[t] = sd[t] - v;        // exclusive
    if (t == NB - 1) rowptr[N] = sd[t];     // total = E + N
}

__global__ void scan_c_kernel(const int* __restrict__ counts, const int* __restrict__ boff,
                              int* __restrict__ rowptr, int N) {
    __shared__ int sd[256];
    int t = threadIdx.x;
    int i = blockIdx.x * 256 + t;
    int v = (i < N) ? counts[i] : 0;
    sd[t] = v;
    __syncthreads();
    for (int o = 1; o < 256; o <<= 1) {
        int x = (t >= o) ? sd[t - o] : 0;
        __syncthreads();
        sd[t] += x;
        __syncthreads();
    }
    if (i < N) rowptr[i] = boff[blockIdx.x] + sd[t] - v;  // exclusive prefix
}

__global__ void scatter_kernel(const int* __restrict__ esrc, const int* __restrict__ edst,
                               const int* __restrict__ rowptr, int* __restrict__ fill,
                               int* __restrict__ csr, int E, int N) {
    int i = blockIdx.x * blockDim.x + threadIdx.x;
    if (i < E) {
        int d = edst[i];
        int pos = rowptr[d] + atomicAdd(&fill[d], 1);
        csr[pos] = esrc[i];
    } else if (i < E + N) {
        int nidx = i - E;  // self loop
        int pos = rowptr[nidx] + atomicAdd(&fill[nidx], 1);
        csr[pos] = nidx;
    }
}

// ------------------------- GEMM (fp32, W in LDS) -------------------------
// Block = 256 threads computes BM rows x FOUT cols; thread tile TM x TN.

template <int FIN, int FOUT, int TM, int TN, int KC>
__launch_bounds__(256)
__global__ void gemm_kernel(const float* __restrict__ X, const float* __restrict__ Wg,
                            float* __restrict__ Hout, int N) {
    constexpr int COLG = FOUT / TN;   // threads covering columns
    constexpr int ROWG = 256 / COLG;  // threads covering rows
    constexpr int BM = ROWG * TM;
    __shared__ float sW[FIN * FOUT];
    __shared__ float sX[BM * (KC + 1)];

    const int tid = threadIdx.x;
    const int tc = tid % COLG;
    const int tr = tid / COLG;
    const int row0 = blockIdx.x * BM;

    for (int idx = tid; idx < FIN * FOUT; idx += 256) sW[idx] = Wg[idx];

    float acc[TM][TN];
#pragma unroll
    for (int i = 0; i < TM; ++i)
#pragma unroll
        for (int j = 0; j < TN; ++j) acc[i][j] = 0.f;

    for (int kc = 0; kc < FIN; kc += KC) {
        __syncthreads();
        for (int idx = tid; idx < BM * KC; idx += 256) {
            int r = idx / KC, k = idx % KC;
            int gr = row0 + r;
            sX[r * (KC + 1) + k] = (gr < N) ? X[(size_t)gr * FIN + kc + k] : 0.f;
        }
        __syncthreads();
#pragma unroll 4
        for (int k = 0; k < KC; ++k) {
            float wv[TN];
#pragma unroll
            for (int j = 0; j < TN; ++j) wv[j] = sW[(kc + k) * FOUT + tc * TN + j];
#pragma unroll
            for (int i = 0; i < TM; ++i) {
                float xv = sX[(tr * TM + i) * (KC + 1) + k];
#pragma unroll
                for (int j = 0; j < TN; ++j) acc[i][j] = fmaf(xv, wv[j], acc[i][j]);
            }
        }
    }

#pragma unroll
    for (int i = 0; i < TM; ++i) {
        int gr = row0 + tr * TM + i;
        if (gr < N) {
#pragma unroll
            for (int j = 0; j < TN; ++j)
                Hout[(size_t)gr * FOUT + tc * TN + j] = acc[i][j];
        }
    }
}

// ------------------------- attention scalars -------------------------
// One wave per (node, head): a_s[n,h] = <h[n,h,:], att_src[h,:]>, same for dst.

template <int C>
__launch_bounds__(256)
__global__ void attn_kernel(const float* __restrict__ Hf, const float* __restrict__ atts,
                            const float* __restrict__ attd, float* __restrict__ a_s,
                            float* __restrict__ a_d, int N) {
    int w = blockIdx.x * 4 + (threadIdx.x >> 6);
    int lane = threadIdx.x & 63;
    int n = w >> 1, h = w & 1;
    if (n >= N) return;
    float s = 0.f, d = 0.f;
    if (lane < C) {
        float v = Hf[(size_t)n * (2 * C) + h * C + lane];
        s = v * atts[h * C + lane];
        d = v * attd[h * C + lane];
    }
#pragma unroll
    for (int o = 32; o > 0; o >>= 1) {
        s += __shfl_xor(s, o);
        d += __shfl_xor(d, o);
    }
    if (lane == 0) {
        a_s[n * 2 + h] = s;
        a_d[n * 2 + h] = d;
    }
}

// ------------------------- gather aggregation -------------------------
// One wave per destination node. H = 2 heads fixed.
// C == 64: lane = channel; per edge load h[src] for both heads.
// C == 32: lane = h*32 + c; single load covers both heads; combine via shfl.

__device__ __forceinline__ float lrelu02(float x) { return x > 0.f ? x : 0.2f * x; }

template <int C, bool ELU>
__launch_bounds__(256)
__global__ void aggregate_kernel(const float* __restrict__ Hf, const float* __restrict__ a_s,
                                 const float* __restrict__ a_d, const int* __restrict__ rowptr,
                                 const int* __restrict__ csr, const float* __restrict__ bias,
                                 float* __restrict__ out, int N) {
    int n = blockIdx.x * 4 + (threadIdx.x >> 6);
    if (n >= N) return;
    int lane = threadIdx.x & 63;
    int start = rowptr[n], end = rowptr[n + 1];

    float2 adn = ((const float2*)a_d)[n];

    // Phase A: segment max of leaky_relu(a_s[src] + a_d[n]) per head
    float m0 = -1e30f, m1 = -1e30f;
    for (int j = start + lane; j < end; j += 64) {
        int s = csr[j];
        float2 asv = ((const float2*)a_s)[s];
        m0 = fmaxf(m0, lrelu02(asv.x + adn.x));
        m1 = fmaxf(m1, lrelu02(asv.y + adn.y));
    }
#pragma unroll
    for (int o = 32; o > 0; o >>= 1) {
        m0 = fmaxf(m0, __shfl_xor(m0, o));
        m1 = fmaxf(m1, __shfl_xor(m1, o));
    }

    // Phase B: unnormalized weighted gather + denom
    float d0 = 0.f, d1 = 0.f;
    float acc0 = 0.f, acc1 = 0.f;
    for (int j = start; j < end; ++j) {
        int s = csr[j];
        float2 asv = ((const float2*)a_s)[s];
        float w0 = expf(lrelu02(asv.x + adn.x) - m0);
        float w1 = expf(lrelu02(asv.y + adn.y) - m1);
        d0 += w0;
        d1 += w1;
        if (C == 64) {
            acc0 += w0 * Hf[(size_t)s * 128 + lane];
            acc1 += w1 * Hf[(size_t)s * 128 + 64 + lane];
        } else {
            float v = Hf[(size_t)s * (2 * C) + lane];
            acc0 += (lane < C ? w0 : w1) * v;
        }
    }

    if (C == 64) {
        float r = 0.5f * (acc0 / d0 + acc1 / d1) + bias[lane];
        if (ELU) r = r > 0.f ? r : expm1f(r);
        out[(size_t)n * C + lane] = r;
    } else {
        float r = acc0 / (lane < C ? d0 : d1);
        r += __shfl_xor(r, 32);  // head0 + head1 for channel (lane & 31)
        if (lane < C) {
            float o = 0.5f * r + bias[lane];
            if (ELU) o = o > 0.f ? o : expm1f(o);
            out[(size_t)n * C + lane] = o;
        }
    }
}

// ------------------------- launch -------------------------

extern "C" void kernel_launch(void* const* d_in, const int* in_sizes, int n_in,
                              void* d_out, int out_size, void* d_ws, size_t ws_size,
                              hipStream_t stream) {
    const float* x    = (const float*)d_in[0];
    const int*   eidx = (const int*)d_in[1];
    const float* W1   = (const float*)d_in[2];
    const float* as1w = (const float*)d_in[3];
    const float* ad1w = (const float*)d_in[4];
    const float* b1   = (const float*)d_in[5];
    const float* W2   = (const float*)d_in[6];
    const float* as2w = (const float*)d_in[7];
    const float* ad2w = (const float*)d_in[8];
    const float* b2   = (const float*)d_in[9];
    float* out = (float*)d_out;

    const int N = in_sizes[0] / 128;  // Fin = 128
    const int E = in_sizes[1] / 2;
    const int NB = (N + 255) / 256;

    char* base = (char*)d_ws;
    size_t off = 0;
    auto alloc = [&](size_t bytes) {
        size_t cur = off;
        off += (bytes + 255) & ~(size_t)255;
        return (void*)(base + cur);
    };

    int* counts   = (int*)alloc((size_t)N * 4);
    int* fill     = (int*)alloc((size_t)N * 4);
    int* bsum     = (int*)alloc((size_t)NB * 4);
    int* boff     = (int*)alloc((size_t)NB * 4);
    int* rowptr   = (int*)alloc((size_t)(N + 1) * 4);
    int* csr      = (int*)alloc((size_t)(E + N) * 4);
    float* h1     = (float*)alloc((size_t)N * 128 * 4);  // reused as h2
    float* x2     = (float*)alloc((size_t)N * 64 * 4);
    float* a_s    = (float*)alloc((size_t)N * 2 * 4);
    float* a_d    = (float*)alloc((size_t)N * 2 * 4);

    const int* esrc = eidx;
    const int* edst = eidx + E;

    // --- CSR build (shared by both layers) ---
    init_kernel<<<(N + 255) / 256, 256, 0, stream>>>(counts, fill, N);
    hist_kernel<<<(E + 255) / 256, 256, 0, stream>>>(edst, counts, E);
    scan_a_kernel<<<NB, 256, 0, stream>>>(counts, bsum, N);
    scan_b_kernel<<<1, 1024, 0, stream>>>(bsum, boff, rowptr, NB, N);
    scan_c_kernel<<<NB, 256, 0, stream>>>(counts, boff, rowptr, N);
    scatter_kernel<<<(E + N + 255) / 256, 256, 0, stream>>>(esrc, edst, rowptr, fill, csr, E, N);

    // --- Layer 1 (Fin=128 -> H=2, C=64) ---
    gemm_kernel<128, 128, 4, 8, 32><<<(N + 63) / 64, 256, 0, stream>>>(x, W1, h1, N);
    attn_kernel<64><<<(2 * N + 3) / 4, 256, 0, stream>>>(h1, as1w, ad1w, a_s, a_d, N);
    aggregate_kernel<64, true><<<(N + 3) / 4, 256, 0, stream>>>(h1, a_s, a_d, rowptr, csr, b1, x2, N);

    // --- Layer 2 (Fin=64 -> H=2, C=32) ---
    gemm_kernel<64, 64, 4, 8, 32><<<(N + 127) / 128, 256, 0, stream>>>(x2, W2, h1, N);
    attn_kernel<32><<<(2 * N + 3) / 4, 256, 0, stream>>>(h1, as2w, ad2w, a_s, a_d, N);
    aggregate_kernel<32, false><<<(N + 3) / 4, 256, 0, stream>>>(h1, a_s, a_d, rowptr, csr, b2, out, N);
}

// Round 2
// 650.094 us; speedup vs baseline: 1.2948x; 1.2948x over previous
//
#include <hip/hip_runtime.h>
#include <hip/hip_bf16.h>
#include <math.h>

// ---------------------------------------------------------------------------
// GAT 2-layer forward, fp32 throughout.
//   1. CSR build by dst (counts -> scan -> scatter), shared by both layers
//   2. h1 = x @ W1            (LDS-tiled fp32 GEMM, W resident in LDS)
//   3. a_s1/a_d1 = <h1, att>
//   4. aggregate1: per-dst gather softmax + weighted sum, +b1, elu -> x2
//   5. h2 = x2 @ W2   6. a_s2/a_d2   7. aggregate2 -> out (+b2, head mean)
// R2: aggregate kernels restructured — per-edge softmax weights computed
//     lane-parallel once per chunk (LDS float4 broadcast), gather uses one
//     dwordx2 load/lane. Removes ~25 redundant VALU ops/edge (VALUBusy 73%).
// ---------------------------------------------------------------------------

// ------------------------- CSR build -------------------------

__global__ void init_kernel(int* __restrict__ counts, int* __restrict__ fill, int N) {
    int i = blockIdx.x * blockDim.x + threadIdx.x;
    if (i < N) { counts[i] = 1; fill[i] = 0; }  // counts starts at 1: self-loop
}

__global__ void hist_kernel(const int* __restrict__ dst, int* __restrict__ counts, int E) {
    int i = blockIdx.x * blockDim.x + threadIdx.x;
    if (i < E) atomicAdd(&counts[dst[i]], 1);
}

__global__ void scan_a_kernel(const int* __restrict__ counts, int* __restrict__ bsum, int N) {
    __shared__ int sd[256];
    int t = threadIdx.x;
    int i = blockIdx.x * 256 + t;
    sd[t] = (i < N) ? counts[i] : 0;
    __syncthreads();
    for (int o = 128; o > 0; o >>= 1) {
        if (t < o) sd[t] += sd[t + o];
        __syncthreads();
    }
    if (t == 0) bsum[blockIdx.x] = sd[0];
}

__launch_bounds__(1024)
__global__ void scan_b_kernel(const int* __restrict__ bsum, int* __restrict__ boff,
                              int* __restrict__ rowptr, int NB, int N) {
    __shared__ int sd[1024];
    int t = threadIdx.x;
    int v = (t < NB) ? bsum[t] : 0;
    sd[t] = v;
    __syncthreads();
    for (int o = 1; o < 1024; o <<= 1) {
        int x = (t >= o) ? sd[t - o] : 0;
        __syncthreads();
        sd[t] += x;
        __syncthreads();
    }
    if (t < NB) boff[t] = sd[t] - v;        // exclusive
    if (t == NB - 1) rowptr[N] = sd[t];     // total = E + N
}

__global__ void scan_c_kernel(const int* __restrict__ counts, const int* __restrict__ boff,
                              int* __restrict__ rowptr, int N) {
    __shared__ int sd[256];
    int t = threadIdx.x;
    int i = blockIdx.x * 256 + t;
    int v = (i < N) ? counts[i] : 0;
    sd[t] = v;
    __syncthreads();
    for (int o = 1; o < 256; o <<= 1) {
        int x = (t >= o) ? sd[t - o] : 0;
        __syncthreads();
        sd[t] += x;
        __syncthreads();
    }
    if (i < N) rowptr[i] = boff[blockIdx.x] + sd[t] - v;  // exclusive prefix
}

__global__ void scatter_kernel(const int* __restrict__ esrc, const int* __restrict__ edst,
                               const int* __restrict__ rowptr, int* __restrict__ fill,
                               int* __restrict__ csr, int E, int N) {
    int i = blockIdx.x * blockDim.x + threadIdx.x;
    if (i < E) {
        int d = edst[i];
        int pos = rowptr[d] + atomicAdd(&fill[d], 1);
        csr[pos] = esrc[i];
    } else if (i < E + N) {
        int nidx = i - E;  // self loop
        int pos = rowptr[nidx] + atomicAdd(&fill[nidx], 1);
        csr[pos] = nidx;
    }
}

// ------------------------- GEMM (fp32, W in LDS) -------------------------

template <int FIN, int FOUT, int TM, int TN, int KC>
__launch_bounds__(256)
__global__ void gemm_kernel(const float* __restrict__ X, const float* __restrict__ Wg,
                            float* __restrict__ Hout, int N) {
    constexpr int COLG = FOUT / TN;   // threads covering columns
    constexpr int ROWG = 256 / COLG;  // threads covering rows
    constexpr int BM = ROWG * TM;
    __shared__ float sW[FIN * FOUT];
    __shared__ float sX[BM * (KC + 1)];

    const int tid = threadIdx.x;
    const int tc = tid % COLG;
    const int tr = tid / COLG;
    const int row0 = blockIdx.x * BM;

    for (int idx = tid; idx < FIN * FOUT; idx += 256) sW[idx] = Wg[idx];

    float acc[TM][TN];
#pragma unroll
    for (int i = 0; i < TM; ++i)
#pragma unroll
        for (int j = 0; j < TN; ++j) acc[i][j] = 0.f;

    for (int kc = 0; kc < FIN; kc += KC) {
        __syncthreads();
        for (int idx = tid; idx < BM * KC; idx += 256) {
            int r = idx / KC, k = idx % KC;
            int gr = row0 + r;
            sX[r * (KC + 1) + k] = (gr < N) ? X[(size_t)gr * FIN + kc + k] : 0.f;
        }
        __syncthreads();
#pragma unroll 4
        for (int k = 0; k < KC; ++k) {
            float wv[TN];
#pragma unroll
            for (int j = 0; j < TN; ++j) wv[j] = sW[(kc + k) * FOUT + tc * TN + j];
#pragma unroll
            for (int i = 0; i < TM; ++i) {
                float xv = sX[(tr * TM + i) * (KC + 1) + k];
#pragma unroll
                for (int j = 0; j < TN; ++j) acc[i][j] = fmaf(xv, wv[j], acc[i][j]);
            }
        }
    }

#pragma unroll
    for (int i = 0; i < TM; ++i) {
        int gr = row0 + tr * TM + i;
        if (gr < N) {
#pragma unroll
            for (int j = 0; j < TN; ++j)
                Hout[(size_t)gr * FOUT + tc * TN + j] = acc[i][j];
        }
    }
}

// ------------------------- attention scalars -------------------------

template <int C>
__launch_bounds__(256)
__global__ void attn_kernel(const float* __restrict__ Hf, const float* __restrict__ atts,
                            const float* __restrict__ attd, float* __restrict__ a_s,
                            float* __restrict__ a_d, int N) {
    int w = blockIdx.x * 4 + (threadIdx.x >> 6);
    int lane = threadIdx.x & 63;
    int n = w >> 1, h = w & 1;
    if (n >= N) return;
    float s = 0.f, d = 0.f;
    if (lane < C) {
        float v = Hf[(size_t)n * (2 * C) + h * C + lane];
        s = v * atts[h * C + lane];
        d = v * attd[h * C + lane];
    }
#pragma unroll
    for (int o = 32; o > 0; o >>= 1) {
        s += __shfl_xor(s, o);
        d += __shfl_xor(d, o);
    }
    if (lane == 0) {
        a_s[n * 2 + h] = s;
        a_d[n * 2 + h] = d;
    }
}

// ------------------------- gather aggregation (R2) -------------------------
// One wave per destination node, H = 2 heads fixed.
// Per-edge softmax weights computed lane-parallel (one edge per lane per
// chunk of 64), packed (w0, w1, src) into one LDS float4, then the whole
// wave gathers serially over the chunk with broadcast ds_read_b128.
// C == 64: lane l holds channel pair (2*(l&31), +1) of head (l>>5) -> one
//          dwordx2 load per edge covers all 128 channels.
// C == 32: lane = h*32 + c; one dword load per edge covers both heads.

__device__ __forceinline__ float lrelu02(float x) { return x > 0.f ? x : 0.2f * x; }

template <int C, bool ELU>
__launch_bounds__(256)
__global__ void aggregate_kernel(const float* __restrict__ Hf, const float* __restrict__ a_s,
                                 const float* __restrict__ a_d, const int* __restrict__ rowptr,
                                 const int* __restrict__ csr, const float* __restrict__ bias,
                                 float* __restrict__ out, int N) {
    __shared__ float4 sw[4][64];
    const int wid = threadIdx.x >> 6;
    const int lane = threadIdx.x & 63;
    int n = blockIdx.x * 4 + wid;
    if (n >= N) return;
    int start = rowptr[n], end = rowptr[n + 1];
    float2 adn = ((const float2*)a_d)[n];

    // Pass 1: per-head running max (lane-parallel, avg degree ~17 -> ~1 iter)
    float m0 = -1e30f, m1 = -1e30f;
    for (int j = start + lane; j < end; j += 64) {
        int s = csr[j];
        float2 asv = ((const float2*)a_s)[s];
        m0 = fmaxf(m0, lrelu02(asv.x + adn.x));
        m1 = fmaxf(m1, lrelu02(asv.y + adn.y));
    }
#pragma unroll
    for (int o = 32; o > 0; o >>= 1) {
        m0 = fmaxf(m0, __shfl_xor(m0, o));
        m1 = fmaxf(m1, __shfl_xor(m1, o));
    }

    float d0 = 0.f, d1 = 0.f;
    float2 acc = make_float2(0.f, 0.f);  // C==64 path
    float acc32 = 0.f;                   // C==32 path
    const float* hp64 = Hf + 2 * lane;   // lane's channel pair base (C==64)
    const float* hp32 = Hf + lane;       // lane's channel base (C==32)

    for (int cs = start; cs < end; cs += 64) {
        int j = cs + lane;
        float w0 = 0.f, w1 = 0.f;
        int s = 0;
        if (j < end) {
            s = csr[j];
            float2 asv = ((const float2*)a_s)[s];
            w0 = __expf(lrelu02(asv.x + adn.x) - m0);
            w1 = __expf(lrelu02(asv.y + adn.y) - m1);
        }
        d0 += w0;  // lane-partial denom, reduced after the loop
        d1 += w1;
        sw[wid][lane] = make_float4(w0, w1, __int_as_float(s), 0.f);
        int cnt = min(64, end - cs);
#pragma unroll 4
        for (int t = 0; t < cnt; ++t) {
            float4 e = sw[wid][t];     // broadcast, conflict-free
            int s2 = __float_as_int(e.z);
            if (C == 64) {
                float2 v = *(const float2*)(hp64 + (size_t)s2 * 128);
                float ww = (lane < 32) ? e.x : e.y;
                acc.x = fmaf(ww, v.x, acc.x);
                acc.y = fmaf(ww, v.y, acc.y);
            } else {
                float v = hp32[(size_t)s2 * 64];
                acc32 = fmaf((lane < 32) ? e.x : e.y, v, acc32);
            }
        }
    }

#pragma unroll
    for (int o = 32; o > 0; o >>= 1) {
        d0 += __shfl_xor(d0, o);
        d1 += __shfl_xor(d1, o);
    }

    if (C == 64) {
        float myd = (lane < 32) ? d0 : d1;
        float rx = acc.x / myd, ry = acc.y / myd;
        // head mean: lane l (head0, ch 2l..2l+1) + lane l+32 (head1, same ch)
        rx += __shfl_xor(rx, 32);
        ry += __shfl_xor(ry, 32);
        if (lane < 32) {
            float2 bv = *(const float2*)(bias + 2 * lane);
            float ox = 0.5f * rx + bv.x;
            float oy = 0.5f * ry + bv.y;
            if (ELU) {
                ox = ox > 0.f ? ox : expm1f(ox);
                oy = oy > 0.f ? oy : expm1f(oy);
            }
            *(float2*)(out + (size_t)n * 64 + 2 * lane) = make_float2(ox, oy);
        }
    } else {
        float r = acc32 / ((lane < 32) ? d0 : d1);
        r += __shfl_xor(r, 32);  // head0 + head1 for channel (lane & 31)
        if (lane < 32) {
            float o = 0.5f * r + bias[lane];
            if (ELU) o = o > 0.f ? o : expm1f(o);
            out[(size_t)n * 32 + lane] = o;
        }
    }
}

// ------------------------- launch -------------------------

extern "C" void kernel_launch(void* const* d_in, const int* in_sizes, int n_in,
                              void* d_out, int out_size, void* d_ws, size_t ws_size,
                              hipStream_t stream) {
    const float* x    = (const float*)d_in[0];
    const int*   eidx = (const int*)d_in[1];
    const float* W1   = (const float*)d_in[2];
    const float* as1w = (const float*)d_in[3];
    const float* ad1w = (const float*)d_in[4];
    const float* b1   = (const float*)d_in[5];
    const float* W2   = (const float*)d_in[6];
    const float* as2w = (const float*)d_in[7];
    const float* ad2w = (const float*)d_in[8];
    const float* b2   = (const float*)d_in[9];
    float* out = (float*)d_out;

    const int N = in_sizes[0] / 128;  // Fin = 128
    const int E = in_sizes[1] / 2;
    const int NB = (N + 255) / 256;

    char* base = (char*)d_ws;
    size_t off = 0;
    auto alloc = [&](size_t bytes) {
        size_t cur = off;
        off += (bytes + 255) & ~(size_t)255;
        return (void*)(base + cur);
    };

    int* counts   = (int*)alloc((size_t)N * 4);
    int* fill     = (int*)alloc((size_t)N * 4);
    int* bsum     = (int*)alloc((size_t)NB * 4);
    int* boff     = (int*)alloc((size_t)NB * 4);
    int* rowptr   = (int*)alloc((size_t)(N + 1) * 4);
    int* csr      = (int*)alloc((size_t)(E + N) * 4);
    float* h1     = (float*)alloc((size_t)N * 128 * 4);  // reused as h2
    float* x2     = (float*)alloc((size_t)N * 64 * 4);
    float* a_s    = (float*)alloc((size_t)N * 2 * 4);
    float* a_d    = (float*)alloc((size_t)N * 2 * 4);

    const int* esrc = eidx;
    const int* edst = eidx + E;

    // --- CSR build (shared by both layers) ---
    init_kernel<<<(N + 255) / 256, 256, 0, stream>>>(counts, fill, N);
    hist_kernel<<<(E + 255) / 256, 256, 0, stream>>>(edst, counts, E);
    scan_a_kernel<<<NB, 256, 0, stream>>>(counts, bsum, N);
    scan_b_kernel<<<1, 1024, 0, stream>>>(bsum, boff, rowptr, NB, N);
    scan_c_kernel<<<NB, 256, 0, stream>>>(counts, boff, rowptr, N);
    scatter_kernel<<<(E + N + 255) / 256, 256, 0, stream>>>(esrc, edst, rowptr, fill, csr, E, N);

    // --- Layer 1 (Fin=128 -> H=2, C=64) ---
    gemm_kernel<128, 128, 4, 8, 32><<<(N + 63) / 64, 256, 0, stream>>>(x, W1, h1, N);
    attn_kernel<64><<<(2 * N + 3) / 4, 256, 0, stream>>>(h1, as1w, ad1w, a_s, a_d, N);
    aggregate_kernel<64, true><<<(N + 3) / 4, 256, 0, stream>>>(h1, a_s, a_d, rowptr, csr, b1, x2, N);

    // --- Layer 2 (Fin=64 -> H=2, C=32) ---
    gemm_kernel<64, 64, 4, 8, 32><<<(N + 127) / 128, 256, 0, stream>>>(x2, W2, h1, N);
    attn_kernel<32><<<(2 * N + 3) / 4, 256, 0, stream>>>(h1, as2w, ad2w, a_s, a_d, N);
    aggregate_kernel<32, false><<<(N + 3) / 4, 256, 0, stream>>>(h1, a_s, a_d, rowptr, csr, b2, out, N);
}

// Round 3
// 527.518 us; speedup vs baseline: 1.5957x; 1.2324x over previous
//
#include <hip/hip_runtime.h>
#include <hip/hip_bf16.h>
#include <hip/hip_fp16.h>
#include <math.h>

// ---------------------------------------------------------------------------
// GAT 2-layer forward. fp32 GEMM + fp32 attention logits; h stored fp16 for
// the edge gather (messages), fp32 accumulation everywhere.
//   1. CSR build by dst (counts -> scan -> scatter), shared by both layers
//   2. h1 = x @ W1 (LDS-tiled fp32 GEMM) -> fp16 h + fused a_s/a_d epilogue
//   3. aggregate1: per-dst gather softmax + weighted sum, +b1, elu -> x2
//   4. h2 = x2 @ W2 (same fusion)   5. aggregate2 -> out (+b2, head mean)
// R3: fp16 gather (halves per-edge bytes), attn fused into GEMM epilogue
//     (removes 2 dispatches + 77 MB of h re-reads), KC-chunked W staging.
// ---------------------------------------------------------------------------

// ------------------------- CSR build -------------------------

__global__ void init_kernel(int* __restrict__ counts, int* __restrict__ fill, int N) {
    int i = blockIdx.x * blockDim.x + threadIdx.x;
    if (i < N) { counts[i] = 1; fill[i] = 0; }  // counts starts at 1: self-loop
}

__global__ void hist_kernel(const int* __restrict__ dst, int* __restrict__ counts, int E) {
    int i = blockIdx.x * blockDim.x + threadIdx.x;
    if (i < E) atomicAdd(&counts[dst[i]], 1);
}

__global__ void scan_a_kernel(const int* __restrict__ counts, int* __restrict__ bsum, int N) {
    __shared__ int sd[256];
    int t = threadIdx.x;
    int i = blockIdx.x * 256 + t;
    sd[t] = (i < N) ? counts[i] : 0;
    __syncthreads();
    for (int o = 128; o > 0; o >>= 1) {
        if (t < o) sd[t] += sd[t + o];
        __syncthreads();
    }
    if (t == 0) bsum[blockIdx.x] = sd[0];
}

__launch_bounds__(1024)
__global__ void scan_b_kernel(const int* __restrict__ bsum, int* __restrict__ boff,
                              int* __restrict__ rowptr, int NB, int N) {
    __shared__ int sd[1024];
    int t = threadIdx.x;
    int v = (t < NB) ? bsum[t] : 0;
    sd[t] = v;
    __syncthreads();
    for (int o = 1; o < 1024; o <<= 1) {
        int x = (t >= o) ? sd[t - o] : 0;
        __syncthreads();
        sd[t] += x;
        __syncthreads();
    }
    if (t < NB) boff[t] = sd[t] - v;        // exclusive
    if (t == NB - 1) rowptr[N] = sd[t];     // total = E + N
}

__global__ void scan_c_kernel(const int* __restrict__ counts, const int* __restrict__ boff,
                              int* __restrict__ rowptr, int N) {
    __shared__ int sd[256];
    int t = threadIdx.x;
    int i = blockIdx.x * 256 + t;
    int v = (i < N) ? counts[i] : 0;
    sd[t] = v;
    __syncthreads();
    for (int o = 1; o < 256; o <<= 1) {
        int x = (t >= o) ? sd[t - o] : 0;
        __syncthreads();
        sd[t] += x;
        __syncthreads();
    }
    if (i < N) rowptr[i] = boff[blockIdx.x] + sd[t] - v;  // exclusive prefix
}

__global__ void scatter_kernel(const int* __restrict__ esrc, const int* __restrict__ edst,
                               const int* __restrict__ rowptr, int* __restrict__ fill,
                               int* __restrict__ csr, int E, int N) {
    int i = blockIdx.x * blockDim.x + threadIdx.x;
    if (i < E) {
        int d = edst[i];
        int pos = rowptr[d] + atomicAdd(&fill[d], 1);
        csr[pos] = esrc[i];
    } else if (i < E + N) {
        int nidx = i - E;  // self loop
        int pos = rowptr[nidx] + atomicAdd(&fill[nidx], 1);
        csr[pos] = nidx;
    }
}

// ------------------- GEMM (fp32) + fused attn epilogue -------------------
// 256 threads compute BM rows x FOUT cols; thread tile TM x TN.
// Epilogue: h -> fp16 (for gather); a_s/a_d from fp32 accumulators via
// in-wave shuffle reduction over the C/TN threads covering each head.

template <int FIN, int FOUT, int C, int TM, int TN, int KC>
__launch_bounds__(256)
__global__ void gemm_attn_kernel(const float* __restrict__ X, const float* __restrict__ Wg,
                                 const float* __restrict__ atts, const float* __restrict__ attd,
                                 __half* __restrict__ Hh, float* __restrict__ a_s,
                                 float* __restrict__ a_d, int N) {
    constexpr int COLG = FOUT / TN;   // threads covering columns (16 / 8)
    constexpr int ROWG = 256 / COLG;  // threads covering rows
    constexpr int BM = ROWG * TM;
    constexpr int HT = C / TN;        // threads per head (8 / 4)
    __shared__ float sW[KC * FOUT];
    __shared__ float sX[BM * (KC + 1)];

    const int tid = threadIdx.x;
    const int tc = tid % COLG;
    const int tr = tid / COLG;
    const int row0 = blockIdx.x * BM;

    float acc[TM][TN];
#pragma unroll
    for (int i = 0; i < TM; ++i)
#pragma unroll
        for (int j = 0; j < TN; ++j) acc[i][j] = 0.f;

    for (int kc = 0; kc < FIN; kc += KC) {
        __syncthreads();
        for (int idx = tid; idx < KC * FOUT; idx += 256)
            sW[idx] = Wg[(size_t)kc * FOUT + idx];
        for (int idx = tid; idx < BM * KC; idx += 256) {
            int r = idx / KC, k = idx % KC;
            int gr = row0 + r;
            sX[r * (KC + 1) + k] = (gr < N) ? X[(size_t)gr * FIN + kc + k] : 0.f;
        }
        __syncthreads();
#pragma unroll 4
        for (int k = 0; k < KC; ++k) {
            float wv[TN];
#pragma unroll
            for (int j = 0; j < TN; ++j) wv[j] = sW[k * FOUT + tc * TN + j];
#pragma unroll
            for (int i = 0; i < TM; ++i) {
                float xv = sX[(tr * TM + i) * (KC + 1) + k];
#pragma unroll
                for (int j = 0; j < TN; ++j) acc[i][j] = fmaf(xv, wv[j], acc[i][j]);
            }
        }
    }

    // ---- epilogue: fp16 h store + attention scalars from fp32 acc ----
    const int head = tc / HT;
    const int colL = (tc % HT) * TN;  // column offset within head
    float attS[TN], attD[TN];
#pragma unroll
    for (int j = 0; j < TN; ++j) {
        attS[j] = atts[head * C + colL + j];
        attD[j] = attd[head * C + colL + j];
    }

#pragma unroll
    for (int i = 0; i < TM; ++i) {
        int gr = row0 + tr * TM + i;
        // fp16 store (TN = 8 halves = 16 B)
        if (gr < N) {
            __half hh[TN];
#pragma unroll
            for (int j = 0; j < TN; ++j) hh[j] = __float2half(acc[i][j]);
            *reinterpret_cast<int4*>(&Hh[(size_t)gr * FOUT + tc * TN]) =
                *reinterpret_cast<const int4*>(hh);
        }
        float ps = 0.f, pd = 0.f;
#pragma unroll
        for (int j = 0; j < TN; ++j) {
            ps = fmaf(acc[i][j], attS[j], ps);
            pd = fmaf(acc[i][j], attD[j], pd);
        }
#pragma unroll
        for (int o = 1; o < HT; o <<= 1) {
            ps += __shfl_xor(ps, o);
            pd += __shfl_xor(pd, o);
        }
        if ((tc % HT) == 0 && gr < N) {
            a_s[gr * 2 + head] = ps;
            a_d[gr * 2 + head] = pd;
        }
    }
}

// ------------------------- gather aggregation -------------------------
// One wave per destination node, H = 2 heads fixed. Per-edge softmax
// weights computed lane-parallel (one edge/lane per chunk of 64), packed
// (w0, w1, src) into LDS float4, then the wave gathers serially with
// broadcast ds_read_b128 + one fp16 global load per lane per edge.
// C == 64: lane l -> head (l>>5), channels 2(l&31), 2(l&31)+1 (half2 load).
// C == 32: lane l -> head (l>>5), channel (l&31) (half load).

__device__ __forceinline__ float lrelu02(float x) { return x > 0.f ? x : 0.2f * x; }

template <int C, bool ELU>
__launch_bounds__(256)
__global__ void aggregate_kernel(const __half* __restrict__ Hh, const float* __restrict__ a_s,
                                 const float* __restrict__ a_d, const int* __restrict__ rowptr,
                                 const int* __restrict__ csr, const float* __restrict__ bias,
                                 float* __restrict__ out, int N) {
    __shared__ float4 sw[4][64];
    const int wid = threadIdx.x >> 6;
    const int lane = threadIdx.x & 63;
    int n = blockIdx.x * 4 + wid;
    if (n >= N) return;
    int start = rowptr[n], end = rowptr[n + 1];
    float2 adn = ((const float2*)a_d)[n];

    // Pass 1: per-head running max
    float m0 = -1e30f, m1 = -1e30f;
    for (int j = start + lane; j < end; j += 64) {
        int s = csr[j];
        float2 asv = ((const float2*)a_s)[s];
        m0 = fmaxf(m0, lrelu02(asv.x + adn.x));
        m1 = fmaxf(m1, lrelu02(asv.y + adn.y));
    }
#pragma unroll
    for (int o = 32; o > 0; o >>= 1) {
        m0 = fmaxf(m0, __shfl_xor(m0, o));
        m1 = fmaxf(m1, __shfl_xor(m1, o));
    }

    float d0 = 0.f, d1 = 0.f;
    float2 acc = make_float2(0.f, 0.f);  // C==64 path
    float acc32 = 0.f;                   // C==32 path

    for (int cs = start; cs < end; cs += 64) {
        int j = cs + lane;
        float w0 = 0.f, w1 = 0.f;
        int s = 0;
        if (j < end) {
            s = csr[j];
            float2 asv = ((const float2*)a_s)[s];
            w0 = __expf(lrelu02(asv.x + adn.x) - m0);
            w1 = __expf(lrelu02(asv.y + adn.y) - m1);
        }
        d0 += w0;  // lane-partial denom, reduced after the loop
        d1 += w1;
        sw[wid][lane] = make_float4(w0, w1, __int_as_float(s), 0.f);
        int cnt = min(64, end - cs);
#pragma unroll 4
        for (int t = 0; t < cnt; ++t) {
            float4 e = sw[wid][t];     // broadcast, conflict-free
            int s2 = __float_as_int(e.z);
            float ww = (lane < 32) ? e.x : e.y;
            if (C == 64) {
                __half2 hv = *((const __half2*)(Hh + (size_t)s2 * 128) + lane);
                float2 v = __half22float2(hv);
                acc.x = fmaf(ww, v.x, acc.x);
                acc.y = fmaf(ww, v.y, acc.y);
            } else {
                float v = __half2float(Hh[(size_t)s2 * 64 + lane]);
                acc32 = fmaf(ww, v, acc32);
            }
        }
    }

#pragma unroll
    for (int o = 32; o > 0; o >>= 1) {
        d0 += __shfl_xor(d0, o);
        d1 += __shfl_xor(d1, o);
    }

    if (C == 64) {
        float myd = (lane < 32) ? d0 : d1;
        float rx = acc.x / myd, ry = acc.y / myd;
        // head mean: lane l (head0, ch 2l..2l+1) + lane l+32 (head1, same ch)
        rx += __shfl_xor(rx, 32);
        ry += __shfl_xor(ry, 32);
        if (lane < 32) {
            float2 bv = *(const float2*)(bias + 2 * lane);
            float ox = 0.5f * rx + bv.x;
            float oy = 0.5f * ry + bv.y;
            if (ELU) {
                ox = ox > 0.f ? ox : expm1f(ox);
                oy = oy > 0.f ? oy : expm1f(oy);
            }
            *(float2*)(out + (size_t)n * 64 + 2 * lane) = make_float2(ox, oy);
        }
    } else {
        float r = acc32 / ((lane < 32) ? d0 : d1);
        r += __shfl_xor(r, 32);  // head0 + head1 for channel (lane & 31)
        if (lane < 32) {
            float o = 0.5f * r + bias[lane];
            if (ELU) o = o > 0.f ? o : expm1f(o);
            out[(size_t)n * 32 + lane] = o;
        }
    }
}

// ------------------------- launch -------------------------

extern "C" void kernel_launch(void* const* d_in, const int* in_sizes, int n_in,
                              void* d_out, int out_size, void* d_ws, size_t ws_size,
                              hipStream_t stream) {
    const float* x    = (const float*)d_in[0];
    const int*   eidx = (const int*)d_in[1];
    const float* W1   = (const float*)d_in[2];
    const float* as1w = (const float*)d_in[3];
    const float* ad1w = (const float*)d_in[4];
    const float* b1   = (const float*)d_in[5];
    const float* W2   = (const float*)d_in[6];
    const float* as2w = (const float*)d_in[7];
    const float* ad2w = (const float*)d_in[8];
    const float* b2   = (const float*)d_in[9];
    float* out = (float*)d_out;

    const int N = in_sizes[0] / 128;  // Fin = 128
    const int E = in_sizes[1] / 2;
    const int NB = (N + 255) / 256;

    char* base = (char*)d_ws;
    size_t off = 0;
    auto alloc = [&](size_t bytes) {
        size_t cur = off;
        off += (bytes + 255) & ~(size_t)255;
        return (void*)(base + cur);
    };

    int* counts   = (int*)alloc((size_t)N * 4);
    int* fill     = (int*)alloc((size_t)N * 4);
    int* bsum     = (int*)alloc((size_t)NB * 4);
    int* boff     = (int*)alloc((size_t)NB * 4);
    int* rowptr   = (int*)alloc((size_t)(N + 1) * 4);
    int* csr      = (int*)alloc((size_t)(E + N) * 4);
    __half* h1    = (__half*)alloc((size_t)N * 128 * 2);  // fp16, reused as h2
    float* x2     = (float*)alloc((size_t)N * 64 * 4);
    float* a_s    = (float*)alloc((size_t)N * 2 * 4);
    float* a_d    = (float*)alloc((size_t)N * 2 * 4);

    const int* esrc = eidx;
    const int* edst = eidx + E;

    // --- CSR build (shared by both layers) ---
    init_kernel<<<(N + 255) / 256, 256, 0, stream>>>(counts, fill, N);
    hist_kernel<<<(E + 255) / 256, 256, 0, stream>>>(edst, counts, E);
    scan_a_kernel<<<NB, 256, 0, stream>>>(counts, bsum, N);
    scan_b_kernel<<<1, 1024, 0, stream>>>(bsum, boff, rowptr, NB, N);
    scan_c_kernel<<<NB, 256, 0, stream>>>(counts, boff, rowptr, N);
    scatter_kernel<<<(E + N + 255) / 256, 256, 0, stream>>>(esrc, edst, rowptr, fill, csr, E, N);

    // --- Layer 1 (Fin=128 -> H=2, C=64) ---
    gemm_attn_kernel<128, 128, 64, 4, 8, 32>
        <<<(N + 63) / 64, 256, 0, stream>>>(x, W1, as1w, ad1w, h1, a_s, a_d, N);
    aggregate_kernel<64, true><<<(N + 3) / 4, 256, 0, stream>>>(h1, a_s, a_d, rowptr, csr, b1, x2, N);

    // --- Layer 2 (Fin=64 -> H=2, C=32) ---
    gemm_attn_kernel<64, 64, 32, 4, 8, 32>
        <<<(N + 127) / 128, 256, 0, stream>>>(x2, W2, as2w, ad2w, h1, a_s, a_d, N);
    aggregate_kernel<32, false><<<(N + 3) / 4, 256, 0, stream>>>(h1, a_s, a_d, rowptr, csr, b2, out, N);
}

// Round 4
// 491.040 us; speedup vs baseline: 1.7142x; 1.0743x over previous
//
#include <hip/hip_runtime.h>
#include <hip/hip_bf16.h>
#include <hip/hip_fp16.h>
#include <math.h>

// ---------------------------------------------------------------------------
// GAT 2-layer forward. fp32 GEMM + fp32 attention logits; h stored fp16 for
// the edge gather (messages), fp32 accumulation everywhere.
//   1. CSR build by dst: node hist -> rowptr scan; bucket hist -> binA
//      (LDS-reordered coarse partition, coalesced) -> binB (LDS-staged
//      per-bucket fine scatter, coalesced). Shared by both layers.
//   2. h1 = x @ W1 (LDS-tiled fp32 GEMM) -> fp16 h + fused a_s/a_d epilogue
//   3. aggregate1: per-dst gather softmax + weighted sum, +b1, elu -> x2
//   4. h2 = x2 @ W2 (same fusion)   5. aggregate2 -> out (+b2, head mean)
// R4: scatter_kernel (109 MB dirty-line writebacks, 105 us) replaced by
//     two-level binned build with fully coalesced global writes.
// ---------------------------------------------------------------------------

#define BINBITS 9                 // nodes per bucket = 512
#define NBUCK 256                 // covers N < 131072
#define CHUNK 4096                // edges per WG in binA
#define SPANCAP 12288             // LDS staging capacity in binB (ints)

// ------------------------- CSR build -------------------------

__global__ void init_kernel(int* __restrict__ counts, int* __restrict__ bcnt, int N) {
    int i = blockIdx.x * blockDim.x + threadIdx.x;
    if (i < N) counts[i] = 1;      // counts starts at 1: self-loop
    if (i < NBUCK) bcnt[i] = 0;
}

__global__ void hist_kernel(const int* __restrict__ dst, int* __restrict__ counts, int E) {
    int i = blockIdx.x * blockDim.x + threadIdx.x;
    if (i < E) atomicAdd(&counts[dst[i]], 1);
}

__global__ void scan_a_kernel(const int* __restrict__ counts, int* __restrict__ bsum, int N) {
    __shared__ int sd[256];
    int t = threadIdx.x;
    int i = blockIdx.x * 256 + t;
    sd[t] = (i < N) ? counts[i] : 0;
    __syncthreads();
    for (int o = 128; o > 0; o >>= 1) {
        if (t < o) sd[t] += sd[t + o];
        __syncthreads();
    }
    if (t == 0) bsum[blockIdx.x] = sd[0];
}

__launch_bounds__(1024)
__global__ void scan_b_kernel(const int* __restrict__ bsum, int* __restrict__ boff,
                              int* __restrict__ rowptr, int NB, int N) {
    __shared__ int sd[1024];
    int t = threadIdx.x;
    int v = (t < NB) ? bsum[t] : 0;
    sd[t] = v;
    __syncthreads();
    for (int o = 1; o < 1024; o <<= 1) {
        int x = (t >= o) ? sd[t - o] : 0;
        __syncthreads();
        sd[t] += x;
        __syncthreads();
    }
    if (t < NB) boff[t] = sd[t] - v;        // exclusive
    if (t == NB - 1) rowptr[N] = sd[t];     // total = E + N
}

__global__ void scan_c_kernel(const int* __restrict__ counts, const int* __restrict__ boff,
                              int* __restrict__ rowptr, int N) {
    __shared__ int sd[256];
    int t = threadIdx.x;
    int i = blockIdx.x * 256 + t;
    int v = (i < N) ? counts[i] : 0;
    sd[t] = v;
    __syncthreads();
    for (int o = 1; o < 256; o <<= 1) {
        int x = (t >= o) ? sd[t - o] : 0;
        __syncthreads();
        sd[t] += x;
        __syncthreads();
    }
    if (i < N) rowptr[i] = boff[blockIdx.x] + sd[t] - v;  // exclusive prefix
}

__global__ void bucket_hist_kernel(const int* __restrict__ dst, int* __restrict__ bcnt, int E) {
    __shared__ int h[NBUCK];
    int t = threadIdx.x;
    h[t] = 0;
    __syncthreads();
    for (int i = blockIdx.x * blockDim.x + t; i < E; i += gridDim.x * blockDim.x)
        atomicAdd(&h[dst[i] >> BINBITS], 1);
    __syncthreads();
    if (h[t]) atomicAdd(&bcnt[t], h[t]);
}

__global__ void bucket_scan_kernel(const int* __restrict__ bcnt, int* __restrict__ bbase,
                                   int* __restrict__ bfill) {
    __shared__ int sd[NBUCK];
    int t = threadIdx.x;
    int v = bcnt[t];
    sd[t] = v;
    __syncthreads();
    for (int o = 1; o < NBUCK; o <<= 1) {
        int x = (t >= o) ? sd[t - o] : 0;
        __syncthreads();
        sd[t] += x;
        __syncthreads();
    }
    int exc = sd[t] - v;
    bbase[t] = exc;
    bfill[t] = exc;
    if (t == NBUCK - 1) bbase[NBUCK] = sd[t];  // = E
}

// binA: coarse partition. Chunk of CHUNK edges -> LDS reorder by bucket ->
// contiguous global segment writes. Packed entry: (dst&511)<<17 | src.
__launch_bounds__(256)
__global__ void binA_kernel(const int* __restrict__ esrc, const int* __restrict__ edst,
                            int* __restrict__ bfill, unsigned* __restrict__ binned, int E) {
    __shared__ unsigned stage[CHUNK];
    __shared__ int hcnt[NBUCK], hexc[NBUCK], gb[NBUCK], hfill[NBUCK];
    const int tid = threadIdx.x;
    const int c0 = blockIdx.x * CHUNK;
    const int n = min(CHUNK, E - c0);

    hcnt[tid] = 0;
    hfill[tid] = 0;
    __syncthreads();
    for (int i = tid; i < n; i += 256) atomicAdd(&hcnt[edst[c0 + i] >> BINBITS], 1);
    __syncthreads();
    int myc = hcnt[tid];
    hexc[tid] = myc;
    __syncthreads();
    for (int o = 1; o < NBUCK; o <<= 1) {       // inclusive scan
        int x = (tid >= o) ? hexc[tid - o] : 0;
        __syncthreads();
        hexc[tid] += x;
        __syncthreads();
    }
    hexc[tid] -= myc;                           // exclusive
    gb[tid] = myc ? atomicAdd(&bfill[tid], myc) : 0;
    __syncthreads();

    for (int i = tid; i < n; i += 256) {
        int d = edst[c0 + i], s = esrc[c0 + i];
        int b = d >> BINBITS;
        int p = hexc[b] + atomicAdd(&hfill[b], 1);
        stage[p] = ((unsigned)(d & ((1 << BINBITS) - 1)) << 17) | (unsigned)s;
    }
    __syncthreads();

    // stream each bucket segment out contiguously (wave w -> buckets [64w,64w+64))
    const int wid = tid >> 6, lane = tid & 63;
    for (int b = wid * 64; b < wid * 64 + 64; ++b) {
        int cnt = hcnt[b], sb = hexc[b], g = gb[b];
        for (int l = lane; l < cnt; l += 64) binned[g + l] = stage[sb + l];
    }
}

// binB: fine scatter within one bucket, staged in LDS, coalesced write-out.
// Self-loops appended here (counts were initialized to 1).
__launch_bounds__(256)
__global__ void binB_kernel(const unsigned* __restrict__ binned, const int* __restrict__ bbase,
                            const int* __restrict__ rowptr, int* __restrict__ csr, int N) {
    __shared__ int rp[(1 << BINBITS) + 1];
    __shared__ int fill[1 << BINBITS];
    __shared__ int stag[SPANCAP];
    const int tid = threadIdx.x;
    const int b = blockIdx.x;
    const int node0 = b << BINBITS;
    if (node0 >= N) return;
    const int nn = min(1 << BINBITS, N - node0);

    for (int i = tid; i <= nn; i += 256) rp[i] = rowptr[node0 + i];
    for (int i = tid; i < nn; i += 256) fill[i] = 0;
    __syncthreads();
    const int r0 = rp[0];
    const int span = rp[nn] - r0;
    const int e0 = bbase[b], e1 = bbase[b + 1];

    if (span <= SPANCAP) {
        for (int i = e0 + tid; i < e1; i += 256) {
            unsigned e = binned[i];
            int dloc = e >> 17, src = e & 0x1FFFF;
            int p = rp[dloc] - r0 + atomicAdd(&fill[dloc], 1);
            stag[p] = src;
        }
        for (int i = tid; i < nn; i += 256) {   // self loops
            int p = rp[i] - r0 + atomicAdd(&fill[i], 1);
            stag[p] = node0 + i;
        }
        __syncthreads();
        for (int i = tid; i < span; i += 256) csr[r0 + i] = stag[i];
    } else {                                    // pathological bucket: direct
        for (int i = e0 + tid; i < e1; i += 256) {
            unsigned e = binned[i];
            int dloc = e >> 17, src = e & 0x1FFFF;
            csr[rp[dloc] + atomicAdd(&fill[dloc], 1)] = src;
        }
        for (int i = tid; i < nn; i += 256)
            csr[rp[i] + atomicAdd(&fill[i], 1)] = node0 + i;
    }
}

// ------------------- GEMM (fp32) + fused attn epilogue -------------------

template <int FIN, int FOUT, int C, int TM, int TN, int KC>
__launch_bounds__(256)
__global__ void gemm_attn_kernel(const float* __restrict__ X, const float* __restrict__ Wg,
                                 const float* __restrict__ atts, const float* __restrict__ attd,
                                 __half* __restrict__ Hh, float* __restrict__ a_s,
                                 float* __restrict__ a_d, int N) {
    constexpr int COLG = FOUT / TN;   // threads covering columns (16 / 8)
    constexpr int ROWG = 256 / COLG;  // threads covering rows
    constexpr int BM = ROWG * TM;
    constexpr int HT = C / TN;        // threads per head (8 / 4)
    __shared__ float sW[KC * FOUT];
    __shared__ float sX[BM * (KC + 1)];

    const int tid = threadIdx.x;
    const int tc = tid % COLG;
    const int tr = tid / COLG;
    const int row0 = blockIdx.x * BM;

    float acc[TM][TN];
#pragma unroll
    for (int i = 0; i < TM; ++i)
#pragma unroll
        for (int j = 0; j < TN; ++j) acc[i][j] = 0.f;

    for (int kc = 0; kc < FIN; kc += KC) {
        __syncthreads();
        for (int idx = tid; idx < KC * FOUT; idx += 256)
            sW[idx] = Wg[(size_t)kc * FOUT + idx];
        for (int idx = tid; idx < BM * KC; idx += 256) {
            int r = idx / KC, k = idx % KC;
            int gr = row0 + r;
            sX[r * (KC + 1) + k] = (gr < N) ? X[(size_t)gr * FIN + kc + k] : 0.f;
        }
        __syncthreads();
#pragma unroll 4
        for (int k = 0; k < KC; ++k) {
            float wv[TN];
#pragma unroll
            for (int j = 0; j < TN; ++j) wv[j] = sW[k * FOUT + tc * TN + j];
#pragma unroll
            for (int i = 0; i < TM; ++i) {
                float xv = sX[(tr * TM + i) * (KC + 1) + k];
#pragma unroll
                for (int j = 0; j < TN; ++j) acc[i][j] = fmaf(xv, wv[j], acc[i][j]);
            }
        }
    }

    // ---- epilogue: fp16 h store + attention scalars from fp32 acc ----
    const int head = tc / HT;
    const int colL = (tc % HT) * TN;  // column offset within head
    float attS[TN], attD[TN];
#pragma unroll
    for (int j = 0; j < TN; ++j) {
        attS[j] = atts[head * C + colL + j];
        attD[j] = attd[head * C + colL + j];
    }

#pragma unroll
    for (int i = 0; i < TM; ++i) {
        int gr = row0 + tr * TM + i;
        if (gr < N) {
            __half hh[TN];
#pragma unroll
            for (int j = 0; j < TN; ++j) hh[j] = __float2half(acc[i][j]);
            *reinterpret_cast<int4*>(&Hh[(size_t)gr * FOUT + tc * TN]) =
                *reinterpret_cast<const int4*>(hh);
        }
        float ps = 0.f, pd = 0.f;
#pragma unroll
        for (int j = 0; j < TN; ++j) {
            ps = fmaf(acc[i][j], attS[j], ps);
            pd = fmaf(acc[i][j], attD[j], pd);
        }
#pragma unroll
        for (int o = 1; o < HT; o <<= 1) {
            ps += __shfl_xor(ps, o);
            pd += __shfl_xor(pd, o);
        }
        if ((tc % HT) == 0 && gr < N) {
            a_s[gr * 2 + head] = ps;
            a_d[gr * 2 + head] = pd;
        }
    }
}

// ------------------------- gather aggregation -------------------------
// One wave per destination node, H = 2 heads fixed. Per-edge softmax
// weights computed lane-parallel (one edge/lane per chunk of 64), packed
// (w0, w1, src) into LDS float4, then the wave gathers serially with
// broadcast ds_read_b128 + one fp16 global load per lane per edge.

__device__ __forceinline__ float lrelu02(float x) { return x > 0.f ? x : 0.2f * x; }

template <int C, bool ELU>
__launch_bounds__(256)
__global__ void aggregate_kernel(const __half* __restrict__ Hh, const float* __restrict__ a_s,
                                 const float* __restrict__ a_d, const int* __restrict__ rowptr,
                                 const int* __restrict__ csr, const float* __restrict__ bias,
                                 float* __restrict__ out, int N) {
    __shared__ float4 sw[4][64];
    const int wid = threadIdx.x >> 6;
    const int lane = threadIdx.x & 63;
    int n = blockIdx.x * 4 + wid;
    if (n >= N) return;
    int start = rowptr[n], end = rowptr[n + 1];
    float2 adn = ((const float2*)a_d)[n];

    // Pass 1: per-head running max
    float m0 = -1e30f, m1 = -1e30f;
    for (int j = start + lane; j < end; j += 64) {
        int s = csr[j];
        float2 asv = ((const float2*)a_s)[s];
        m0 = fmaxf(m0, lrelu02(asv.x + adn.x));
        m1 = fmaxf(m1, lrelu02(asv.y + adn.y));
    }
#pragma unroll
    for (int o = 32; o > 0; o >>= 1) {
        m0 = fmaxf(m0, __shfl_xor(m0, o));
        m1 = fmaxf(m1, __shfl_xor(m1, o));
    }

    float d0 = 0.f, d1 = 0.f;
    float2 acc = make_float2(0.f, 0.f);  // C==64 path
    float acc32 = 0.f;                   // C==32 path

    for (int cs = start; cs < end; cs += 64) {
        int j = cs + lane;
        float w0 = 0.f, w1 = 0.f;
        int s = 0;
        if (j < end) {
            s = csr[j];
            float2 asv = ((const float2*)a_s)[s];
            w0 = __expf(lrelu02(asv.x + adn.x) - m0);
            w1 = __expf(lrelu02(asv.y + adn.y) - m1);
        }
        d0 += w0;  // lane-partial denom, reduced after the loop
        d1 += w1;
        sw[wid][lane] = make_float4(w0, w1, __int_as_float(s), 0.f);
        int cnt = min(64, end - cs);
#pragma unroll 4
        for (int t = 0; t < cnt; ++t) {
            float4 e = sw[wid][t];     // broadcast, conflict-free
            int s2 = __float_as_int(e.z);
            float ww = (lane < 32) ? e.x : e.y;
            if (C == 64) {
                __half2 hv = *((const __half2*)(Hh + (size_t)s2 * 128) + lane);
                float2 v = __half22float2(hv);
                acc.x = fmaf(ww, v.x, acc.x);
                acc.y = fmaf(ww, v.y, acc.y);
            } else {
                float v = __half2float(Hh[(size_t)s2 * 64 + lane]);
                acc32 = fmaf(ww, v, acc32);
            }
        }
    }

#pragma unroll
    for (int o = 32; o > 0; o >>= 1) {
        d0 += __shfl_xor(d0, o);
        d1 += __shfl_xor(d1, o);
    }

    if (C == 64) {
        float myd = (lane < 32) ? d0 : d1;
        float rx = acc.x / myd, ry = acc.y / myd;
        rx += __shfl_xor(rx, 32);  // head mean across lane halves
        ry += __shfl_xor(ry, 32);
        if (lane < 32) {
            float2 bv = *(const float2*)(bias + 2 * lane);
            float ox = 0.5f * rx + bv.x;
            float oy = 0.5f * ry + bv.y;
            if (ELU) {
                ox = ox > 0.f ? ox : expm1f(ox);
                oy = oy > 0.f ? oy : expm1f(oy);
            }
            *(float2*)(out + (size_t)n * 64 + 2 * lane) = make_float2(ox, oy);
        }
    } else {
        float r = acc32 / ((lane < 32) ? d0 : d1);
        r += __shfl_xor(r, 32);  // head0 + head1 for channel (lane & 31)
        if (lane < 32) {
            float o = 0.5f * r + bias[lane];
            if (ELU) o = o > 0.f ? o : expm1f(o);
            out[(size_t)n * 32 + lane] = o;
        }
    }
}

// ------------------------- launch -------------------------

extern "C" void kernel_launch(void* const* d_in, const int* in_sizes, int n_in,
                              void* d_out, int out_size, void* d_ws, size_t ws_size,
                              hipStream_t stream) {
    const float* x    = (const float*)d_in[0];
    const int*   eidx = (const int*)d_in[1];
    const float* W1   = (const float*)d_in[2];
    const float* as1w = (const float*)d_in[3];
    const float* ad1w = (const float*)d_in[4];
    const float* b1   = (const float*)d_in[5];
    const float* W2   = (const float*)d_in[6];
    const float* as2w = (const float*)d_in[7];
    const float* ad2w = (const float*)d_in[8];
    const float* b2   = (const float*)d_in[9];
    float* out = (float*)d_out;

    const int N = in_sizes[0] / 128;  // Fin = 128
    const int E = in_sizes[1] / 2;
    const int NB = (N + 255) / 256;
    const int NBK = (N + (1 << BINBITS) - 1) >> BINBITS;

    char* base = (char*)d_ws;
    size_t off = 0;
    auto alloc = [&](size_t bytes) {
        size_t cur = off;
        off += (bytes + 255) & ~(size_t)255;
        return (void*)(base + cur);
    };

    int* counts   = (int*)alloc((size_t)N * 4);
    int* bsum     = (int*)alloc((size_t)NB * 4);
    int* boff     = (int*)alloc((size_t)NB * 4);
    int* rowptr   = (int*)alloc((size_t)(N + 1) * 4);
    int* csr      = (int*)alloc((size_t)(E + N) * 4);
    int* bcnt     = (int*)alloc((size_t)NBUCK * 4);
    int* bbase    = (int*)alloc((size_t)(NBUCK + 1) * 4);
    int* bfill    = (int*)alloc((size_t)NBUCK * 4);
    unsigned* binned = (unsigned*)alloc((size_t)E * 4);
    __half* h1    = (__half*)alloc((size_t)N * 128 * 2);  // fp16, reused as h2
    float* x2     = (float*)alloc((size_t)N * 64 * 4);
    float* a_s    = (float*)alloc((size_t)N * 2 * 4);
    float* a_d    = (float*)alloc((size_t)N * 2 * 4);

    const int* esrc = eidx;
    const int* edst = eidx + E;

    // --- CSR build (shared by both layers) ---
    init_kernel<<<(N + 255) / 256, 256, 0, stream>>>(counts, bcnt, N);
    hist_kernel<<<(E + 255) / 256, 256, 0, stream>>>(edst, counts, E);
    bucket_hist_kernel<<<256, 256, 0, stream>>>(edst, bcnt, E);
    scan_a_kernel<<<NB, 256, 0, stream>>>(counts, bsum, N);
    scan_b_kernel<<<1, 1024, 0, stream>>>(bsum, boff, rowptr, NB, N);
    scan_c_kernel<<<NB, 256, 0, stream>>>(counts, boff, rowptr, N);
    bucket_scan_kernel<<<1, NBUCK, 0, stream>>>(bcnt, bbase, bfill);
    binA_kernel<<<(E + CHUNK - 1) / CHUNK, 256, 0, stream>>>(esrc, edst, bfill, binned, E);
    binB_kernel<<<NBK, 256, 0, stream>>>(binned, bbase, rowptr, csr, N);

    // --- Layer 1 (Fin=128 -> H=2, C=64) ---
    gemm_attn_kernel<128, 128, 64, 4, 8, 32>
        <<<(N + 63) / 64, 256, 0, stream>>>(x, W1, as1w, ad1w, h1, a_s, a_d, N);
    aggregate_kernel<64, true><<<(N + 3) / 4, 256, 0, stream>>>(h1, a_s, a_d, rowptr, csr, b1, x2, N);

    // --- Layer 2 (Fin=64 -> H=2, C=32) ---
    gemm_attn_kernel<64, 64, 32, 4, 8, 32>
        <<<(N + 127) / 128, 256, 0, stream>>>(x2, W2, as2w, ad2w, h1, a_s, a_d, N);
    aggregate_kernel<32, false><<<(N + 3) / 4, 256, 0, stream>>>(h1, a_s, a_d, rowptr, csr, b2, out, N);
}

// Round 5
// 438.162 us; speedup vs baseline: 1.9211x; 1.1207x over previous
//
#include <hip/hip_runtime.h>
#include <hip/hip_bf16.h>
#include <hip/hip_fp16.h>
#include <math.h>

// ---------------------------------------------------------------------------
// GAT 2-layer forward. fp32 GEMM + fp32 attention logits; h stored fp16 for
// the edge gather (messages), fp32 accumulation everywhere.
// R5: gemm_attn rewritten (transposed sX for b128 row loads, split col-quads
//     -> conflict-free LDS, 64 FMA : 4 b128 per k -> VALU-bound);
//     aggregate inner loop pipelined in groups of 8 (8 outstanding gathers,
//     per-head float2 LDS records, no per-edge cndmask).
// ---------------------------------------------------------------------------

#define BINBITS 9                 // nodes per bucket = 512
#define NBUCK 256                 // covers N < 131072
#define CHUNK 4096                // edges per WG in binA
#define SPANCAP 12288             // LDS staging capacity in binB (ints)

// ------------------------- CSR build -------------------------

__global__ void init_kernel(int* __restrict__ counts, int* __restrict__ bcnt, int N) {
    int i = blockIdx.x * blockDim.x + threadIdx.x;
    if (i < N) counts[i] = 1;      // counts starts at 1: self-loop
    if (i < NBUCK) bcnt[i] = 0;
}

__global__ void hist_kernel(const int* __restrict__ dst, int* __restrict__ counts, int E) {
    int i = blockIdx.x * blockDim.x + threadIdx.x;
    if (i < E) atomicAdd(&counts[dst[i]], 1);
}

__global__ void scan_a_kernel(const int* __restrict__ counts, int* __restrict__ bsum, int N) {
    __shared__ int sd[256];
    int t = threadIdx.x;
    int i = blockIdx.x * 256 + t;
    sd[t] = (i < N) ? counts[i] : 0;
    __syncthreads();
    for (int o = 128; o > 0; o >>= 1) {
        if (t < o) sd[t] += sd[t + o];
        __syncthreads();
    }
    if (t == 0) bsum[blockIdx.x] = sd[0];
}

__launch_bounds__(1024)
__global__ void scan_b_kernel(const int* __restrict__ bsum, int* __restrict__ boff,
                              int* __restrict__ rowptr, int NB, int N) {
    __shared__ int sd[1024];
    int t = threadIdx.x;
    int v = (t < NB) ? bsum[t] : 0;
    sd[t] = v;
    __syncthreads();
    for (int o = 1; o < 1024; o <<= 1) {
        int x = (t >= o) ? sd[t - o] : 0;
        __syncthreads();
        sd[t] += x;
        __syncthreads();
    }
    if (t < NB) boff[t] = sd[t] - v;        // exclusive
    if (t == NB - 1) rowptr[N] = sd[t];     // total = E + N
}

__global__ void scan_c_kernel(const int* __restrict__ counts, const int* __restrict__ boff,
                              int* __restrict__ rowptr, int N) {
    __shared__ int sd[256];
    int t = threadIdx.x;
    int i = blockIdx.x * 256 + t;
    int v = (i < N) ? counts[i] : 0;
    sd[t] = v;
    __syncthreads();
    for (int o = 1; o < 256; o <<= 1) {
        int x = (t >= o) ? sd[t - o] : 0;
        __syncthreads();
        sd[t] += x;
        __syncthreads();
    }
    if (i < N) rowptr[i] = boff[blockIdx.x] + sd[t] - v;  // exclusive prefix
}

__global__ void bucket_hist_kernel(const int* __restrict__ dst, int* __restrict__ bcnt, int E) {
    __shared__ int h[NBUCK];
    int t = threadIdx.x;
    h[t] = 0;
    __syncthreads();
    for (int i = blockIdx.x * blockDim.x + t; i < E; i += gridDim.x * blockDim.x)
        atomicAdd(&h[dst[i] >> BINBITS], 1);
    __syncthreads();
    if (h[t]) atomicAdd(&bcnt[t], h[t]);
}

__global__ void bucket_scan_kernel(const int* __restrict__ bcnt, int* __restrict__ bbase,
                                   int* __restrict__ bfill) {
    __shared__ int sd[NBUCK];
    int t = threadIdx.x;
    int v = bcnt[t];
    sd[t] = v;
    __syncthreads();
    for (int o = 1; o < NBUCK; o <<= 1) {
        int x = (t >= o) ? sd[t - o] : 0;
        __syncthreads();
        sd[t] += x;
        __syncthreads();
    }
    int exc = sd[t] - v;
    bbase[t] = exc;
    bfill[t] = exc;
    if (t == NBUCK - 1) bbase[NBUCK] = sd[t];  // = E
}

// binA: coarse partition. Chunk of CHUNK edges -> LDS reorder by bucket ->
// contiguous global segment writes. Packed entry: (dst&511)<<17 | src.
__launch_bounds__(256)
__global__ void binA_kernel(const int* __restrict__ esrc, const int* __restrict__ edst,
                            int* __restrict__ bfill, unsigned* __restrict__ binned, int E) {
    __shared__ unsigned stage[CHUNK];
    __shared__ int hcnt[NBUCK], hexc[NBUCK], gb[NBUCK], hfill[NBUCK];
    const int tid = threadIdx.x;
    const int c0 = blockIdx.x * CHUNK;
    const int n = min(CHUNK, E - c0);

    hcnt[tid] = 0;
    hfill[tid] = 0;
    __syncthreads();
    for (int i = tid; i < n; i += 256) atomicAdd(&hcnt[edst[c0 + i] >> BINBITS], 1);
    __syncthreads();
    int myc = hcnt[tid];
    hexc[tid] = myc;
    __syncthreads();
    for (int o = 1; o < NBUCK; o <<= 1) {       // inclusive scan
        int x = (tid >= o) ? hexc[tid - o] : 0;
        __syncthreads();
        hexc[tid] += x;
        __syncthreads();
    }
    hexc[tid] -= myc;                           // exclusive
    gb[tid] = myc ? atomicAdd(&bfill[tid], myc) : 0;
    __syncthreads();

    for (int i = tid; i < n; i += 256) {
        int d = edst[c0 + i], s = esrc[c0 + i];
        int b = d >> BINBITS;
        int p = hexc[b] + atomicAdd(&hfill[b], 1);
        stage[p] = ((unsigned)(d & ((1 << BINBITS) - 1)) << 17) | (unsigned)s;
    }
    __syncthreads();

    // stream each bucket segment out contiguously (wave w -> buckets [64w,64w+64))
    const int wid = tid >> 6, lane = tid & 63;
    for (int b = wid * 64; b < wid * 64 + 64; ++b) {
        int cnt = hcnt[b], sb = hexc[b], g = gb[b];
        for (int l = lane; l < cnt; l += 64) binned[g + l] = stage[sb + l];
    }
}

// binB: fine scatter within one bucket, staged in LDS, coalesced write-out.
__launch_bounds__(256)
__global__ void binB_kernel(const unsigned* __restrict__ binned, const int* __restrict__ bbase,
                            const int* __restrict__ rowptr, int* __restrict__ csr, int N) {
    __shared__ int rp[(1 << BINBITS) + 1];
    __shared__ int fill[1 << BINBITS];
    __shared__ int stag[SPANCAP];
    const int tid = threadIdx.x;
    const int b = blockIdx.x;
    const int node0 = b << BINBITS;
    if (node0 >= N) return;
    const int nn = min(1 << BINBITS, N - node0);

    for (int i = tid; i <= nn; i += 256) rp[i] = rowptr[node0 + i];
    for (int i = tid; i < nn; i += 256) fill[i] = 0;
    __syncthreads();
    const int r0 = rp[0];
    const int span = rp[nn] - r0;
    const int e0 = bbase[b], e1 = bbase[b + 1];

    if (span <= SPANCAP) {
        for (int i = e0 + tid; i < e1; i += 256) {
            unsigned e = binned[i];
            int dloc = e >> 17, src = e & 0x1FFFF;
            int p = rp[dloc] - r0 + atomicAdd(&fill[dloc], 1);
            stag[p] = src;
        }
        for (int i = tid; i < nn; i += 256) {   // self loops
            int p = rp[i] - r0 + atomicAdd(&fill[i], 1);
            stag[p] = node0 + i;
        }
        __syncthreads();
        for (int i = tid; i < span; i += 256) csr[r0 + i] = stag[i];
    } else {                                    // pathological bucket: direct
        for (int i = e0 + tid; i < e1; i += 256) {
            unsigned e = binned[i];
            int dloc = e >> 17, src = e & 0x1FFFF;
            csr[rp[dloc] + atomicAdd(&fill[dloc], 1)] = src;
        }
        for (int i = tid; i < nn; i += 256)
            csr[rp[i] + atomicAdd(&fill[i], 1)] = node0 + i;
    }
}

// ------------------- GEMM (fp32) + fused attn epilogue -------------------
// 256 threads, BM = 128 rows, FOUT cols. Thread tile: TM rows x (4+4) cols,
// the two col-quads at tc*4 (head 0) and FOUT/2 + tc*4 (head 1).
// sX stored transposed [k][row] (pitch BM+4) so the TM-row slice is b128.

template <int FIN, int FOUT, int TM, int KC>
__launch_bounds__(256)
__global__ void gemm_attn_kernel(const float* __restrict__ X, const float* __restrict__ Wg,
                                 const float* __restrict__ atts, const float* __restrict__ attd,
                                 __half* __restrict__ Hh, float* __restrict__ a_s,
                                 float* __restrict__ a_d, int N) {
    constexpr int COLG = FOUT / 8;    // threads covering columns (16 / 8)
    constexpr int ROWG = 256 / COLG;  // threads covering rows (16 / 32)
    constexpr int BM = ROWG * TM;     // 128
    constexpr int C = FOUT / 2;       // head dim
    constexpr int PR = BM + 4;        // sX pitch (rows)
    __shared__ float sW[KC * FOUT];
    __shared__ float sX[KC * PR];

    const int tid = threadIdx.x;
    const int tc = tid % COLG;
    const int tr = tid / COLG;
    const int row0 = blockIdx.x * BM;

    float accA[TM][4], accB[TM][4];
#pragma unroll
    for (int i = 0; i < TM; ++i)
#pragma unroll
        for (int j = 0; j < 4; ++j) { accA[i][j] = 0.f; accB[i][j] = 0.f; }

    for (int kc = 0; kc < FIN; kc += KC) {
        __syncthreads();
        // stage W chunk: sW[k][c]
        for (int idx = tid; idx < KC * FOUT / 4; idx += 256) {
            int k = idx / (FOUT / 4), cq = idx % (FOUT / 4);
            *(float4*)&sW[k * FOUT + cq * 4] =
                *(const float4*)&Wg[(size_t)(kc + k) * FOUT + cq * 4];
        }
        // stage X chunk transposed: sX[k][r]
        for (int idx = tid; idx < BM * KC / 4; idx += 256) {
            int r = idx / (KC / 4), kq = idx % (KC / 4);
            int gr = row0 + r;
            float4 v = make_float4(0.f, 0.f, 0.f, 0.f);
            if (gr < N) v = *(const float4*)&X[(size_t)gr * FIN + kc + kq * 4];
            sX[(kq * 4 + 0) * PR + r] = v.x;
            sX[(kq * 4 + 1) * PR + r] = v.y;
            sX[(kq * 4 + 2) * PR + r] = v.z;
            sX[(kq * 4 + 3) * PR + r] = v.w;
        }
        __syncthreads();
#pragma unroll 4
        for (int k = 0; k < KC; ++k) {
            float xv[TM];
#pragma unroll
            for (int q = 0; q < TM / 4; ++q)
                *(float4*)&xv[q * 4] = *(const float4*)&sX[k * PR + tr * TM + q * 4];
            float wa[4], wb[4];
            *(float4*)wa = *(const float4*)&sW[k * FOUT + tc * 4];
            *(float4*)wb = *(const float4*)&sW[k * FOUT + C + tc * 4];
#pragma unroll
            for (int i = 0; i < TM; ++i) {
#pragma unroll
                for (int j = 0; j < 4; ++j) {
                    accA[i][j] = fmaf(xv[i], wa[j], accA[i][j]);
                    accB[i][j] = fmaf(xv[i], wb[j], accB[i][j]);
                }
            }
        }
    }

    // ---- epilogue: fp16 h store + attention scalars from fp32 acc ----
    float aSA[4], aSB[4], aDA[4], aDB[4];
#pragma unroll
    for (int j = 0; j < 4; ++j) {
        aSA[j] = atts[tc * 4 + j];        // head 0
        aSB[j] = atts[C + tc * 4 + j];    // head 1
        aDA[j] = attd[tc * 4 + j];
        aDB[j] = attd[C + tc * 4 + j];
    }

#pragma unroll
    for (int i = 0; i < TM; ++i) {
        int gr = row0 + tr * TM + i;
        if (gr < N) {
            union { int2 i2; __half2 h2[2]; } u;
            u.h2[0] = __halves2half2(__float2half(accA[i][0]), __float2half(accA[i][1]));
            u.h2[1] = __halves2half2(__float2half(accA[i][2]), __float2half(accA[i][3]));
            *reinterpret_cast<int2*>(&Hh[(size_t)gr * FOUT + tc * 4]) = u.i2;
            u.h2[0] = __halves2half2(__float2half(accB[i][0]), __float2half(accB[i][1]));
            u.h2[1] = __halves2half2(__float2half(accB[i][2]), __float2half(accB[i][3]));
            *reinterpret_cast<int2*>(&Hh[(size_t)gr * FOUT + C + tc * 4]) = u.i2;
        }
        float ps0 = 0.f, ps1 = 0.f, pd0 = 0.f, pd1 = 0.f;
#pragma unroll
        for (int j = 0; j < 4; ++j) {
            ps0 = fmaf(accA[i][j], aSA[j], ps0);
            ps1 = fmaf(accB[i][j], aSB[j], ps1);
            pd0 = fmaf(accA[i][j], aDA[j], pd0);
            pd1 = fmaf(accB[i][j], aDB[j], pd1);
        }
#pragma unroll
        for (int o = 1; o < COLG; o <<= 1) {
            ps0 += __shfl_xor(ps0, o);
            ps1 += __shfl_xor(ps1, o);
            pd0 += __shfl_xor(pd0, o);
            pd1 += __shfl_xor(pd1, o);
        }
        if (tc == 0 && gr < N) {
            *(float2*)&a_s[gr * 2] = make_float2(ps0, ps1);
            *(float2*)&a_d[gr * 2] = make_float2(pd0, pd1);
        }
    }
}

// ------------------------- gather aggregation -------------------------
// One wave per destination node, H = 2 heads fixed. Weight phase: lane j
// computes edge j's (w0, w1, src), writes per-head float2(w, src) records
// to LDS (w=0 for OOB lanes -> padded entries are no-ops). Gather phase:
// groups of 8 edges, all 8 global loads issued before any use (8 MLP).
// C == 64: lane -> half2 (channels 2(l&31), +1) of head (l>>5).
// C == 32: lane -> half (channel l&31) of head (l>>5).

__device__ __forceinline__ float lrelu02(float x) { return x > 0.f ? x : 0.2f * x; }

template <int C, bool ELU>
__launch_bounds__(256)
__global__ void aggregate_kernel(const __half* __restrict__ Hh, const float* __restrict__ a_s,
                                 const float* __restrict__ a_d, const int* __restrict__ rowptr,
                                 const int* __restrict__ csr, const float* __restrict__ bias,
                                 float* __restrict__ out, int N) {
    __shared__ float2 swH[4][2][64];
    const int wid = threadIdx.x >> 6;
    const int lane = threadIdx.x & 63;
    const int hh = lane >> 5;          // this lane's head
    int n = blockIdx.x * 4 + wid;
    if (n >= N) return;
    int start = rowptr[n], end = rowptr[n + 1];
    float2 adn = ((const float2*)a_d)[n];

    // Pass 1: per-head running max
    float m0 = -1e30f, m1 = -1e30f;
    for (int j = start + lane; j < end; j += 64) {
        int s = csr[j];
        float2 asv = ((const float2*)a_s)[s];
        m0 = fmaxf(m0, lrelu02(asv.x + adn.x));
        m1 = fmaxf(m1, lrelu02(asv.y + adn.y));
    }
#pragma unroll
    for (int o = 32; o > 0; o >>= 1) {
        m0 = fmaxf(m0, __shfl_xor(m0, o));
        m1 = fmaxf(m1, __shfl_xor(m1, o));
    }

    float d0 = 0.f, d1 = 0.f;
    float2 acc = make_float2(0.f, 0.f);  // C==64 path
    float acc32 = 0.f;                   // C==32 path

    for (int cs = start; cs < end; cs += 64) {
        int j = cs + lane;
        float w0 = 0.f, w1 = 0.f;
        int s = 0;
        if (j < end) {
            s = csr[j];
            float2 asv = ((const float2*)a_s)[s];
            w0 = __expf(lrelu02(asv.x + adn.x) - m0);
            w1 = __expf(lrelu02(asv.y + adn.y) - m1);
        }
        d0 += w0;  // lane-partial denom, reduced after the loop
        d1 += w1;
        swH[wid][0][lane] = make_float2(w0, __int_as_float(s));
        swH[wid][1][lane] = make_float2(w1, __int_as_float(s));
        int cnt = min(64, end - cs);
        for (int t0 = 0; t0 < cnt; t0 += 8) {
            float2 e[8];
#pragma unroll
            for (int u = 0; u < 8; ++u) e[u] = swH[wid][hh][t0 + u];  // <= 63: safe, padded w=0
            if (C == 64) {
                __half2 hv[8];
#pragma unroll
                for (int u = 0; u < 8; ++u) {
                    int s2 = __float_as_int(e[u].y);
                    hv[u] = *((const __half2*)Hh + (size_t)s2 * 64 + lane);
                }
#pragma unroll
                for (int u = 0; u < 8; ++u) {
                    float2 v = __half22float2(hv[u]);
                    acc.x = fmaf(e[u].x, v.x, acc.x);
                    acc.y = fmaf(e[u].x, v.y, acc.y);
                }
            } else {
                __half hv[8];
#pragma unroll
                for (int u = 0; u < 8; ++u) {
                    int s2 = __float_as_int(e[u].y);
                    hv[u] = Hh[(size_t)s2 * 64 + lane];
                }
#pragma unroll
                for (int u = 0; u < 8; ++u)
                    acc32 = fmaf(e[u].x, __half2float(hv[u]), acc32);
            }
        }
    }

#pragma unroll
    for (int o = 32; o > 0; o >>= 1) {
        d0 += __shfl_xor(d0, o);
        d1 += __shfl_xor(d1, o);
    }

    if (C == 64) {
        float myd = (lane < 32) ? d0 : d1;
        float rx = acc.x / myd, ry = acc.y / myd;
        rx += __shfl_xor(rx, 32);  // head mean across lane halves
        ry += __shfl_xor(ry, 32);
        if (lane < 32) {
            float2 bv = *(const float2*)(bias + 2 * lane);
            float ox = 0.5f * rx + bv.x;
            float oy = 0.5f * ry + bv.y;
            if (ELU) {
                ox = ox > 0.f ? ox : expm1f(ox);
                oy = oy > 0.f ? oy : expm1f(oy);
            }
            *(float2*)(out + (size_t)n * 64 + 2 * lane) = make_float2(ox, oy);
        }
    } else {
        float r = acc32 / ((lane < 32) ? d0 : d1);
        r += __shfl_xor(r, 32);  // head0 + head1 for channel (lane & 31)
        if (lane < 32) {
            float o = 0.5f * r + bias[lane];
            if (ELU) o = o > 0.f ? o : expm1f(o);
            out[(size_t)n * 32 + lane] = o;
        }
    }
}

// ------------------------- launch -------------------------

extern "C" void kernel_launch(void* const* d_in, const int* in_sizes, int n_in,
                              void* d_out, int out_size, void* d_ws, size_t ws_size,
                              hipStream_t stream) {
    const float* x    = (const float*)d_in[0];
    const int*   eidx = (const int*)d_in[1];
    const float* W1   = (const float*)d_in[2];
    const float* as1w = (const float*)d_in[3];
    const float* ad1w = (const float*)d_in[4];
    const float* b1   = (const float*)d_in[5];
    const float* W2   = (const float*)d_in[6];
    const float* as2w = (const float*)d_in[7];
    const float* ad2w = (const float*)d_in[8];
    const float* b2   = (const float*)d_in[9];
    float* out = (float*)d_out;

    const int N = in_sizes[0] / 128;  // Fin = 128
    const int E = in_sizes[1] / 2;
    const int NB = (N + 255) / 256;
    const int NBK = (N + (1 << BINBITS) - 1) >> BINBITS;

    char* base = (char*)d_ws;
    size_t off = 0;
    auto alloc = [&](size_t bytes) {
        size_t cur = off;
        off += (bytes + 255) & ~(size_t)255;
        return (void*)(base + cur);
    };

    int* counts   = (int*)alloc((size_t)N * 4);
    int* bsum     = (int*)alloc((size_t)NB * 4);
    int* boff     = (int*)alloc((size_t)NB * 4);
    int* rowptr   = (int*)alloc((size_t)(N + 1) * 4);
    int* csr      = (int*)alloc((size_t)(E + N) * 4);
    int* bcnt     = (int*)alloc((size_t)NBUCK * 4);
    int* bbase    = (int*)alloc((size_t)(NBUCK + 1) * 4);
    int* bfill    = (int*)alloc((size_t)NBUCK * 4);
    unsigned* binned = (unsigned*)alloc((size_t)E * 4);
    __half* h1    = (__half*)alloc((size_t)N * 128 * 2);  // fp16, reused as h2
    float* x2     = (float*)alloc((size_t)N * 64 * 4);
    float* a_s    = (float*)alloc((size_t)N * 2 * 4);
    float* a_d    = (float*)alloc((size_t)N * 2 * 4);

    const int* esrc = eidx;
    const int* edst = eidx + E;

    // --- CSR build (shared by both layers) ---
    init_kernel<<<(N + 255) / 256, 256, 0, stream>>>(counts, bcnt, N);
    hist_kernel<<<(E + 255) / 256, 256, 0, stream>>>(edst, counts, E);
    bucket_hist_kernel<<<256, 256, 0, stream>>>(edst, bcnt, E);
    scan_a_kernel<<<NB, 256, 0, stream>>>(counts, bsum, N);
    scan_b_kernel<<<1, 1024, 0, stream>>>(bsum, boff, rowptr, NB, N);
    scan_c_kernel<<<NB, 256, 0, stream>>>(counts, boff, rowptr, N);
    bucket_scan_kernel<<<1, NBUCK, 0, stream>>>(bcnt, bbase, bfill);
    binA_kernel<<<(E + CHUNK - 1) / CHUNK, 256, 0, stream>>>(esrc, edst, bfill, binned, E);
    binB_kernel<<<NBK, 256, 0, stream>>>(binned, bbase, rowptr, csr, N);

    // --- Layer 1 (Fin=128 -> H=2, C=64) ---
    gemm_attn_kernel<128, 128, 8, 32>
        <<<(N + 127) / 128, 256, 0, stream>>>(x, W1, as1w, ad1w, h1, a_s, a_d, N);
    aggregate_kernel<64, true><<<(N + 3) / 4, 256, 0, stream>>>(h1, a_s, a_d, rowptr, csr, b1, x2, N);

    // --- Layer 2 (Fin=64 -> H=2, C=32) ---
    gemm_attn_kernel<64, 64, 4, 32>
        <<<(N + 127) / 128, 256, 0, stream>>>(x2, W2, as2w, ad2w, h1, a_s, a_d, N);
    aggregate_kernel<32, false><<<(N + 3) / 4, 256, 0, stream>>>(h1, a_s, a_d, rowptr, csr, b2, out, N);
}

// Round 6
// 430.315 us; speedup vs baseline: 1.9561x; 1.0182x over previous
//
#include <hip/hip_runtime.h>
#include <hip/hip_bf16.h>
#include <hip/hip_fp16.h>
#include <math.h>

// ---------------------------------------------------------------------------
// GAT 2-layer forward. fp32 GEMM + fp32 attention logits; h stored fp16 for
// the edge gather (messages), fp32 accumulation everywhere.
// R6: aggregate processes TWO edges per wave-instruction (half-wave per edge
//     slot, 4ch/lane via ushort4 in L1, 2ch/lane via half2 in L2) and drops
//     the segment-max pass (softmax is shift-invariant; logits are O(1)).
// ---------------------------------------------------------------------------

#define BINBITS 9                 // nodes per bucket = 512
#define NBUCK 256                 // covers N < 131072
#define CHUNK 4096                // edges per WG in binA
#define SPANCAP 12288             // LDS staging capacity in binB (ints)

// ------------------------- CSR build -------------------------

__global__ void init_kernel(int* __restrict__ counts, int* __restrict__ bcnt, int N) {
    int i = blockIdx.x * blockDim.x + threadIdx.x;
    if (i < N) counts[i] = 1;      // counts starts at 1: self-loop
    if (i < NBUCK) bcnt[i] = 0;
}

__global__ void hist_kernel(const int* __restrict__ dst, int* __restrict__ counts, int E) {
    int i = blockIdx.x * blockDim.x + threadIdx.x;
    if (i < E) atomicAdd(&counts[dst[i]], 1);
}

__global__ void scan_a_kernel(const int* __restrict__ counts, int* __restrict__ bsum, int N) {
    __shared__ int sd[256];
    int t = threadIdx.x;
    int i = blockIdx.x * 256 + t;
    sd[t] = (i < N) ? counts[i] : 0;
    __syncthreads();
    for (int o = 128; o > 0; o >>= 1) {
        if (t < o) sd[t] += sd[t + o];
        __syncthreads();
    }
    if (t == 0) bsum[blockIdx.x] = sd[0];
}

__launch_bounds__(1024)
__global__ void scan_b_kernel(const int* __restrict__ bsum, int* __restrict__ boff,
                              int* __restrict__ rowptr, int NB, int N) {
    __shared__ int sd[1024];
    int t = threadIdx.x;
    int v = (t < NB) ? bsum[t] : 0;
    sd[t] = v;
    __syncthreads();
    for (int o = 1; o < 1024; o <<= 1) {
        int x = (t >= o) ? sd[t - o] : 0;
        __syncthreads();
        sd[t] += x;
        __syncthreads();
    }
    if (t < NB) boff[t] = sd[t] - v;        // exclusive
    if (t == NB - 1) rowptr[N] = sd[t];     // total = E + N
}

__global__ void scan_c_kernel(const int* __restrict__ counts, const int* __restrict__ boff,
                              int* __restrict__ rowptr, int N) {
    __shared__ int sd[256];
    int t = threadIdx.x;
    int i = blockIdx.x * 256 + t;
    int v = (i < N) ? counts[i] : 0;
    sd[t] = v;
    __syncthreads();
    for (int o = 1; o < 256; o <<= 1) {
        int x = (t >= o) ? sd[t - o] : 0;
        __syncthreads();
        sd[t] += x;
        __syncthreads();
    }
    if (i < N) rowptr[i] = boff[blockIdx.x] + sd[t] - v;  // exclusive prefix
}

__global__ void bucket_hist_kernel(const int* __restrict__ dst, int* __restrict__ bcnt, int E) {
    __shared__ int h[NBUCK];
    int t = threadIdx.x;
    h[t] = 0;
    __syncthreads();
    for (int i = blockIdx.x * blockDim.x + t; i < E; i += gridDim.x * blockDim.x)
        atomicAdd(&h[dst[i] >> BINBITS], 1);
    __syncthreads();
    if (h[t]) atomicAdd(&bcnt[t], h[t]);
}

__global__ void bucket_scan_kernel(const int* __restrict__ bcnt, int* __restrict__ bbase,
                                   int* __restrict__ bfill) {
    __shared__ int sd[NBUCK];
    int t = threadIdx.x;
    int v = bcnt[t];
    sd[t] = v;
    __syncthreads();
    for (int o = 1; o < NBUCK; o <<= 1) {
        int x = (t >= o) ? sd[t - o] : 0;
        __syncthreads();
        sd[t] += x;
        __syncthreads();
    }
    int exc = sd[t] - v;
    bbase[t] = exc;
    bfill[t] = exc;
    if (t == NBUCK - 1) bbase[NBUCK] = sd[t];  // = E
}

// binA: coarse partition. Chunk of CHUNK edges -> LDS reorder by bucket ->
// contiguous global segment writes. Packed entry: (dst&511)<<17 | src.
__launch_bounds__(256)
__global__ void binA_kernel(const int* __restrict__ esrc, const int* __restrict__ edst,
                            int* __restrict__ bfill, unsigned* __restrict__ binned, int E) {
    __shared__ unsigned stage[CHUNK];
    __shared__ int hcnt[NBUCK], hexc[NBUCK], gb[NBUCK], hfill[NBUCK];
    const int tid = threadIdx.x;
    const int c0 = blockIdx.x * CHUNK;
    const int n = min(CHUNK, E - c0);

    hcnt[tid] = 0;
    hfill[tid] = 0;
    __syncthreads();
    for (int i = tid; i < n; i += 256) atomicAdd(&hcnt[edst[c0 + i] >> BINBITS], 1);
    __syncthreads();
    int myc = hcnt[tid];
    hexc[tid] = myc;
    __syncthreads();
    for (int o = 1; o < NBUCK; o <<= 1) {       // inclusive scan
        int x = (tid >= o) ? hexc[tid - o] : 0;
        __syncthreads();
        hexc[tid] += x;
        __syncthreads();
    }
    hexc[tid] -= myc;                           // exclusive
    gb[tid] = myc ? atomicAdd(&bfill[tid], myc) : 0;
    __syncthreads();

    for (int i = tid; i < n; i += 256) {
        int d = edst[c0 + i], s = esrc[c0 + i];
        int b = d >> BINBITS;
        int p = hexc[b] + atomicAdd(&hfill[b], 1);
        stage[p] = ((unsigned)(d & ((1 << BINBITS) - 1)) << 17) | (unsigned)s;
    }
    __syncthreads();

    // stream each bucket segment out contiguously (wave w -> buckets [64w,64w+64))
    const int wid = tid >> 6, lane = tid & 63;
    for (int b = wid * 64; b < wid * 64 + 64; ++b) {
        int cnt = hcnt[b], sb = hexc[b], g = gb[b];
        for (int l = lane; l < cnt; l += 64) binned[g + l] = stage[sb + l];
    }
}

// binB: fine scatter within one bucket, staged in LDS, coalesced write-out.
__launch_bounds__(256)
__global__ void binB_kernel(const unsigned* __restrict__ binned, const int* __restrict__ bbase,
                            const int* __restrict__ rowptr, int* __restrict__ csr, int N) {
    __shared__ int rp[(1 << BINBITS) + 1];
    __shared__ int fill[1 << BINBITS];
    __shared__ int stag[SPANCAP];
    const int tid = threadIdx.x;
    const int b = blockIdx.x;
    const int node0 = b << BINBITS;
    if (node0 >= N) return;
    const int nn = min(1 << BINBITS, N - node0);

    for (int i = tid; i <= nn; i += 256) rp[i] = rowptr[node0 + i];
    for (int i = tid; i < nn; i += 256) fill[i] = 0;
    __syncthreads();
    const int r0 = rp[0];
    const int span = rp[nn] - r0;
    const int e0 = bbase[b], e1 = bbase[b + 1];

    if (span <= SPANCAP) {
        for (int i = e0 + tid; i < e1; i += 256) {
            unsigned e = binned[i];
            int dloc = e >> 17, src = e & 0x1FFFF;
            int p = rp[dloc] - r0 + atomicAdd(&fill[dloc], 1);
            stag[p] = src;
        }
        for (int i = tid; i < nn; i += 256) {   // self loops
            int p = rp[i] - r0 + atomicAdd(&fill[i], 1);
            stag[p] = node0 + i;
        }
        __syncthreads();
        for (int i = tid; i < span; i += 256) csr[r0 + i] = stag[i];
    } else {                                    // pathological bucket: direct
        for (int i = e0 + tid; i < e1; i += 256) {
            unsigned e = binned[i];
            int dloc = e >> 17, src = e & 0x1FFFF;
            csr[rp[dloc] + atomicAdd(&fill[dloc], 1)] = src;
        }
        for (int i = tid; i < nn; i += 256)
            csr[rp[i] + atomicAdd(&fill[i], 1)] = node0 + i;
    }
}

// ------------------- GEMM (fp32) + fused attn epilogue -------------------
// 256 threads, BM = 128 rows, FOUT cols. Thread tile: TM rows x (4+4) cols,
// the two col-quads at tc*4 (head 0) and FOUT/2 + tc*4 (head 1).
// sX stored transposed [k][row] (pitch BM+4) so the TM-row slice is b128.

template <int FIN, int FOUT, int TM, int KC>
__launch_bounds__(256)
__global__ void gemm_attn_kernel(const float* __restrict__ X, const float* __restrict__ Wg,
                                 const float* __restrict__ atts, const float* __restrict__ attd,
                                 __half* __restrict__ Hh, float* __restrict__ a_s,
                                 float* __restrict__ a_d, int N) {
    constexpr int COLG = FOUT / 8;    // threads covering columns (16 / 8)
    constexpr int ROWG = 256 / COLG;  // threads covering rows (16 / 32)
    constexpr int BM = ROWG * TM;     // 128
    constexpr int C = FOUT / 2;       // head dim
    constexpr int PR = BM + 4;        // sX pitch (rows)
    __shared__ float sW[KC * FOUT];
    __shared__ float sX[KC * PR];

    const int tid = threadIdx.x;
    const int tc = tid % COLG;
    const int tr = tid / COLG;
    const int row0 = blockIdx.x * BM;

    float accA[TM][4], accB[TM][4];
#pragma unroll
    for (int i = 0; i < TM; ++i)
#pragma unroll
        for (int j = 0; j < 4; ++j) { accA[i][j] = 0.f; accB[i][j] = 0.f; }

    for (int kc = 0; kc < FIN; kc += KC) {
        __syncthreads();
        // stage W chunk: sW[k][c]
        for (int idx = tid; idx < KC * FOUT / 4; idx += 256) {
            int k = idx / (FOUT / 4), cq = idx % (FOUT / 4);
            *(float4*)&sW[k * FOUT + cq * 4] =
                *(const float4*)&Wg[(size_t)(kc + k) * FOUT + cq * 4];
        }
        // stage X chunk transposed: sX[k][r]
        for (int idx = tid; idx < BM * KC / 4; idx += 256) {
            int r = idx / (KC / 4), kq = idx % (KC / 4);
            int gr = row0 + r;
            float4 v = make_float4(0.f, 0.f, 0.f, 0.f);
            if (gr < N) v = *(const float4*)&X[(size_t)gr * FIN + kc + kq * 4];
            sX[(kq * 4 + 0) * PR + r] = v.x;
            sX[(kq * 4 + 1) * PR + r] = v.y;
            sX[(kq * 4 + 2) * PR + r] = v.z;
            sX[(kq * 4 + 3) * PR + r] = v.w;
        }
        __syncthreads();
#pragma unroll 4
        for (int k = 0; k < KC; ++k) {
            float xv[TM];
#pragma unroll
            for (int q = 0; q < TM / 4; ++q)
                *(float4*)&xv[q * 4] = *(const float4*)&sX[k * PR + tr * TM + q * 4];
            float wa[4], wb[4];
            *(float4*)wa = *(const float4*)&sW[k * FOUT + tc * 4];
            *(float4*)wb = *(const float4*)&sW[k * FOUT + C + tc * 4];
#pragma unroll
            for (int i = 0; i < TM; ++i) {
#pragma unroll
                for (int j = 0; j < 4; ++j) {
                    accA[i][j] = fmaf(xv[i], wa[j], accA[i][j]);
                    accB[i][j] = fmaf(xv[i], wb[j], accB[i][j]);
                }
            }
        }
    }

    // ---- epilogue: fp16 h store + attention scalars from fp32 acc ----
    float aSA[4], aSB[4], aDA[4], aDB[4];
#pragma unroll
    for (int j = 0; j < 4; ++j) {
        aSA[j] = atts[tc * 4 + j];        // head 0
        aSB[j] = atts[C + tc * 4 + j];    // head 1
        aDA[j] = attd[tc * 4 + j];
        aDB[j] = attd[C + tc * 4 + j];
    }

#pragma unroll
    for (int i = 0; i < TM; ++i) {
        int gr = row0 + tr * TM + i;
        if (gr < N) {
            union { int2 i2; __half2 h2[2]; } u;
            u.h2[0] = __halves2half2(__float2half(accA[i][0]), __float2half(accA[i][1]));
            u.h2[1] = __halves2half2(__float2half(accA[i][2]), __float2half(accA[i][3]));
            *reinterpret_cast<int2*>(&Hh[(size_t)gr * FOUT + tc * 4]) = u.i2;
            u.h2[0] = __halves2half2(__float2half(accB[i][0]), __float2half(accB[i][1]));
            u.h2[1] = __halves2half2(__float2half(accB[i][2]), __float2half(accB[i][3]));
            *reinterpret_cast<int2*>(&Hh[(size_t)gr * FOUT + C + tc * 4]) = u.i2;
        }
        float ps0 = 0.f, ps1 = 0.f, pd0 = 0.f, pd1 = 0.f;
#pragma unroll
        for (int j = 0; j < 4; ++j) {
            ps0 = fmaf(accA[i][j], aSA[j], ps0);
            ps1 = fmaf(accB[i][j], aSB[j], ps1);
            pd0 = fmaf(accA[i][j], aDA[j], pd0);
            pd1 = fmaf(accB[i][j], aDB[j], pd1);
        }
#pragma unroll
        for (int o = 1; o < COLG; o <<= 1) {
            ps0 += __shfl_xor(ps0, o);
            ps1 += __shfl_xor(ps1, o);
            pd0 += __shfl_xor(pd0, o);
            pd1 += __shfl_xor(pd1, o);
        }
        if (tc == 0 && gr < N) {
            *(float2*)&a_s[gr * 2] = make_float2(ps0, ps1);
            *(float2*)&a_d[gr * 2] = make_float2(pd0, pd1);
        }
    }
}

// ------------------------- gather aggregation (R6) -------------------------
// One wave per destination node, H = 2 heads fixed. Weight phase: lane j
// computes edge j's (w0, w1, src) -- NO max subtraction (softmax is shift-
// invariant; logits here are O(1), exp cannot overflow fp32) -- and stores
// per-head float2(w, src) records in LDS (w=0 for OOB slots).
// Gather phase: TWO edges per wave-instruction. Lanes 0-31 take even edge
// slots, 32-63 odd slots; within a half-wave, sub 0-15 -> head 0, 16-31 ->
// head 1, each lane carrying 4 channels (ushort4, C=64) or 2 (half2, C=32).
// Groups of 4 slot-pairs keep 4 gathers in flight. Final merges: shfl 32
// (edge subsets), shfl 16 (head mean).

__device__ __forceinline__ float lrelu02(float x) { return x > 0.f ? x : 0.2f * x; }

template <int C, bool ELU>
__launch_bounds__(256)
__global__ void aggregate_kernel(const __half* __restrict__ Hh, const float* __restrict__ a_s,
                                 const float* __restrict__ a_d, const int* __restrict__ rowptr,
                                 const int* __restrict__ csr, const float* __restrict__ bias,
                                 float* __restrict__ out, int N) {
    __shared__ float2 swH[4][64][2];   // [wave][slot][head] = (w, src-bits)
    const int wid = threadIdx.x >> 6;
    const int lane = threadIdx.x & 63;
    const int hp = lane >> 5;          // which edge of a slot-pair
    const int sub = lane & 31;
    const int head = sub >> 4;
    const int chq = sub & 15;          // channel quad (C=64) / pair (C=32)
    int n = blockIdx.x * 4 + wid;
    if (n >= N) return;
    int start = rowptr[n], end = rowptr[n + 1];
    float2 adn = ((const float2*)a_d)[n];

    float d0 = 0.f, d1 = 0.f;
    float acc0 = 0.f, acc1 = 0.f, acc2 = 0.f, acc3 = 0.f;

    for (int cs = start; cs < end; cs += 64) {
        int j = cs + lane;
        float w0 = 0.f, w1 = 0.f;
        int s = 0;
        if (j < end) {
            s = csr[j];
            float2 asv = ((const float2*)a_s)[s];
            w0 = __expf(lrelu02(asv.x + adn.x));
            w1 = __expf(lrelu02(asv.y + adn.y));
        }
        d0 += w0;  // lane-partial denom, reduced after the loop
        d1 += w1;
        float fs = __int_as_float(s);
        swH[wid][lane][0] = make_float2(w0, fs);
        swH[wid][lane][1] = make_float2(w1, fs);
        int cnt = min(64, end - cs);
        int npair = (cnt + 1) >> 1;    // <= 32; slot 2p+hp <= 63 always
        for (int p0 = 0; p0 < npair; p0 += 4) {
            float2 e[4];
#pragma unroll
            for (int u = 0; u < 4; ++u)
                e[u] = swH[wid][2 * (p0 + u) + hp][head];  // padded slots: w=0
            if (C == 64) {
                ushort4 hv[4];
#pragma unroll
                for (int u = 0; u < 4; ++u)
                    hv[u] = ((const ushort4*)Hh)[(size_t)__float_as_int(e[u].y) * 32 + sub];
#pragma unroll
                for (int u = 0; u < 4; ++u) {
                    const __half* hx = (const __half*)&hv[u];
                    acc0 = fmaf(e[u].x, __half2float(hx[0]), acc0);
                    acc1 = fmaf(e[u].x, __half2float(hx[1]), acc1);
                    acc2 = fmaf(e[u].x, __half2float(hx[2]), acc2);
                    acc3 = fmaf(e[u].x, __half2float(hx[3]), acc3);
                }
            } else {
                __half2 hv[4];
#pragma unroll
                for (int u = 0; u < 4; ++u)
                    hv[u] = ((const __half2*)Hh)[(size_t)__float_as_int(e[u].y) * 32 + sub];
#pragma unroll
                for (int u = 0; u < 4; ++u) {
                    float2 v = __half22float2(hv[u]);
                    acc0 = fmaf(e[u].x, v.x, acc0);
                    acc1 = fmaf(e[u].x, v.y, acc1);
                }
            }
        }
    }

#pragma unroll
    for (int o = 32; o > 0; o >>= 1) {
        d0 += __shfl_xor(d0, o);
        d1 += __shfl_xor(d1, o);
    }

    // merge the two edge subsets (even/odd slots)
    acc0 += __shfl_xor(acc0, 32);
    acc1 += __shfl_xor(acc1, 32);
    if (C == 64) {
        acc2 += __shfl_xor(acc2, 32);
        acc3 += __shfl_xor(acc3, 32);
    }
    float inv = 1.0f / (head == 0 ? d0 : d1);
    acc0 *= inv; acc1 *= inv;
    if (C == 64) { acc2 *= inv; acc3 *= inv; }
    // head mean: sub s (head0) + sub s+16 (head1), same channels
    acc0 += __shfl_xor(acc0, 16);
    acc1 += __shfl_xor(acc1, 16);
    if (C == 64) {
        acc2 += __shfl_xor(acc2, 16);
        acc3 += __shfl_xor(acc3, 16);
    }

    if (lane < 16) {
        if (C == 64) {
            float4 bv = *(const float4*)(bias + chq * 4);
            float o0 = 0.5f * acc0 + bv.x;
            float o1 = 0.5f * acc1 + bv.y;
            float o2 = 0.5f * acc2 + bv.z;
            float o3 = 0.5f * acc3 + bv.w;
            if (ELU) {
                o0 = o0 > 0.f ? o0 : expm1f(o0);
                o1 = o1 > 0.f ? o1 : expm1f(o1);
                o2 = o2 > 0.f ? o2 : expm1f(o2);
                o3 = o3 > 0.f ? o3 : expm1f(o3);
            }
            *(float4*)(out + (size_t)n * 64 + chq * 4) = make_float4(o0, o1, o2, o3);
        } else {
            float2 bv = *(const float2*)(bias + chq * 2);
            float o0 = 0.5f * acc0 + bv.x;
            float o1 = 0.5f * acc1 + bv.y;
            if (ELU) {
                o0 = o0 > 0.f ? o0 : expm1f(o0);
                o1 = o1 > 0.f ? o1 : expm1f(o1);
            }
            *(float2*)(out + (size_t)n * 32 + chq * 2) = make_float2(o0, o1);
        }
    }
}

// ------------------------- launch -------------------------

extern "C" void kernel_launch(void* const* d_in, const int* in_sizes, int n_in,
                              void* d_out, int out_size, void* d_ws, size_t ws_size,
                              hipStream_t stream) {
    const float* x    = (const float*)d_in[0];
    const int*   eidx = (const int*)d_in[1];
    const float* W1   = (const float*)d_in[2];
    const float* as1w = (const float*)d_in[3];
    const float* ad1w = (const float*)d_in[4];
    const float* b1   = (const float*)d_in[5];
    const float* W2   = (const float*)d_in[6];
    const float* as2w = (const float*)d_in[7];
    const float* ad2w = (const float*)d_in[8];
    const float* b2   = (const float*)d_in[9];
    float* out = (float*)d_out;

    const int N = in_sizes[0] / 128;  // Fin = 128
    const int E = in_sizes[1] / 2;
    const int NB = (N + 255) / 256;
    const int NBK = (N + (1 << BINBITS) - 1) >> BINBITS;

    char* base = (char*)d_ws;
    size_t off = 0;
    auto alloc = [&](size_t bytes) {
        size_t cur = off;
        off += (bytes + 255) & ~(size_t)255;
        return (void*)(base + cur);
    };

    int* counts   = (int*)alloc((size_t)N * 4);
    int* bsum     = (int*)alloc((size_t)NB * 4);
    int* boff     = (int*)alloc((size_t)NB * 4);
    int* rowptr   = (int*)alloc((size_t)(N + 1) * 4);
    int* csr      = (int*)alloc((size_t)(E + N) * 4);
    int* bcnt     = (int*)alloc((size_t)NBUCK * 4);
    int* bbase    = (int*)alloc((size_t)(NBUCK + 1) * 4);
    int* bfill    = (int*)alloc((size_t)NBUCK * 4);
    unsigned* binned = (unsigned*)alloc((size_t)E * 4);
    __half* h1    = (__half*)alloc((size_t)N * 128 * 2);  // fp16, reused as h2
    float* x2     = (float*)alloc((size_t)N * 64 * 4);
    float* a_s    = (float*)alloc((size_t)N * 2 * 4);
    float* a_d    = (float*)alloc((size_t)N * 2 * 4);

    const int* esrc = eidx;
    const int* edst = eidx + E;

    // --- CSR build (shared by both layers) ---
    init_kernel<<<(N + 255) / 256, 256, 0, stream>>>(counts, bcnt, N);
    hist_kernel<<<(E + 255) / 256, 256, 0, stream>>>(edst, counts, E);
    bucket_hist_kernel<<<256, 256, 0, stream>>>(edst, bcnt, E);
    scan_a_kernel<<<NB, 256, 0, stream>>>(counts, bsum, N);
    scan_b_kernel<<<1, 1024, 0, stream>>>(bsum, boff, rowptr, NB, N);
    scan_c_kernel<<<NB, 256, 0, stream>>>(counts, boff, rowptr, N);
    bucket_scan_kernel<<<1, NBUCK, 0, stream>>>(bcnt, bbase, bfill);
    binA_kernel<<<(E + CHUNK - 1) / CHUNK, 256, 0, stream>>>(esrc, edst, bfill, binned, E);
    binB_kernel<<<NBK, 256, 0, stream>>>(binned, bbase, rowptr, csr, N);

    // --- Layer 1 (Fin=128 -> H=2, C=64) ---
    gemm_attn_kernel<128, 128, 8, 32>
        <<<(N + 127) / 128, 256, 0, stream>>>(x, W1, as1w, ad1w, h1, a_s, a_d, N);
    aggregate_kernel<64, true><<<(N + 3) / 4, 256, 0, stream>>>(h1, a_s, a_d, rowptr, csr, b1, x2, N);

    // --- Layer 2 (Fin=64 -> H=2, C=32) ---
    gemm_attn_kernel<64, 64, 4, 32>
        <<<(N + 127) / 128, 256, 0, stream>>>(x2, W2, as2w, ad2w, h1, a_s, a_d, N);
    aggregate_kernel<32, false><<<(N + 3) / 4, 256, 0, stream>>>(h1, a_s, a_d, rowptr, csr, b2, out, N);
}

// Round 7
// 396.925 us; speedup vs baseline: 2.1207x; 1.0841x over previous
//
#include <hip/hip_runtime.h>
#include <hip/hip_bf16.h>
#include <hip/hip_fp16.h>
#include <math.h>

// ---------------------------------------------------------------------------
// GAT 2-layer forward. fp32 GEMM + fp32 attention logits; h stored fp16 for
// the edge gather (messages), fp32 accumulation everywhere.
// R7: (a) softmax weights precomputed NORMALIZED per edge (edge_w kernel,
//     coalesced) -> aggregate is a pure weighted gather (no a_s gather, no
//     exp, no division on its critical path);
//     (b) CSR build collapsed: binB derives rowptr locally per bucket
//     (hist_kernel + scan_a/b/c removed, 4 dispatches fewer).
// ---------------------------------------------------------------------------

#define BINBITS 9                 // nodes per bucket = 512
#define NBUCK 256                 // covers N < 131072
#define CHUNK 4096                // edges per WG in binA
#define SPANCAP 12288             // LDS staging capacity in binB (ints)

// ------------------------- CSR build -------------------------

__global__ void init_kernel(int* __restrict__ bcnt) {
    bcnt[threadIdx.x] = 0;
}

__global__ void bucket_hist_kernel(const int* __restrict__ dst, int* __restrict__ bcnt, int E) {
    __shared__ int h[NBUCK];
    int t = threadIdx.x;
    h[t] = 0;
    __syncthreads();
    for (int i = blockIdx.x * blockDim.x + t; i < E; i += gridDim.x * blockDim.x)
        atomicAdd(&h[dst[i] >> BINBITS], 1);
    __syncthreads();
    if (h[t]) atomicAdd(&bcnt[t], h[t]);
}

__global__ void bucket_scan_kernel(const int* __restrict__ bcnt, int* __restrict__ bbase,
                                   int* __restrict__ bfill) {
    __shared__ int sd[NBUCK];
    int t = threadIdx.x;
    int v = bcnt[t];
    sd[t] = v;
    __syncthreads();
    for (int o = 1; o < NBUCK; o <<= 1) {
        int x = (t >= o) ? sd[t - o] : 0;
        __syncthreads();
        sd[t] += x;
        __syncthreads();
    }
    int exc = sd[t] - v;
    bbase[t] = exc;
    bfill[t] = exc;
    if (t == NBUCK - 1) bbase[NBUCK] = sd[t];  // = E
}

// binA: coarse partition. Chunk of CHUNK edges -> LDS reorder by bucket ->
// contiguous global segment writes. Packed entry: (dst&511)<<17 | src.
__launch_bounds__(256)
__global__ void binA_kernel(const int* __restrict__ esrc, const int* __restrict__ edst,
                            int* __restrict__ bfill, unsigned* __restrict__ binned, int E) {
    __shared__ unsigned stage[CHUNK];
    __shared__ int hcnt[NBUCK], hexc[NBUCK], gb[NBUCK], hfill[NBUCK];
    const int tid = threadIdx.x;
    const int c0 = blockIdx.x * CHUNK;
    const int n = min(CHUNK, E - c0);

    hcnt[tid] = 0;
    hfill[tid] = 0;
    __syncthreads();
    for (int i = tid; i < n; i += 256) atomicAdd(&hcnt[edst[c0 + i] >> BINBITS], 1);
    __syncthreads();
    int myc = hcnt[tid];
    hexc[tid] = myc;
    __syncthreads();
    for (int o = 1; o < NBUCK; o <<= 1) {       // inclusive scan
        int x = (tid >= o) ? hexc[tid - o] : 0;
        __syncthreads();
        hexc[tid] += x;
        __syncthreads();
    }
    hexc[tid] -= myc;                           // exclusive
    gb[tid] = myc ? atomicAdd(&bfill[tid], myc) : 0;
    __syncthreads();

    for (int i = tid; i < n; i += 256) {
        int d = edst[c0 + i], s = esrc[c0 + i];
        int b = d >> BINBITS;
        int p = hexc[b] + atomicAdd(&hfill[b], 1);
        stage[p] = ((unsigned)(d & ((1 << BINBITS) - 1)) << 17) | (unsigned)s;
    }
    __syncthreads();

    // stream each bucket segment out contiguously (wave w -> buckets [64w,64w+64))
    const int wid = tid >> 6, lane = tid & 63;
    for (int b = wid * 64; b < wid * 64 + 64; ++b) {
        int cnt = hcnt[b], sb = hexc[b], g = gb[b];
        for (int l = lane; l < cnt; l += 64) binned[g + l] = stage[sb + l];
    }
}

// binB: per bucket -- LDS histogram of local degrees (incl. self-loop),
// local scan -> rowptr segment (rowptr[node0+i] = bbase[b] + node0 + excl[i],
// exact since every node owns exactly 1 self-loop), then LDS-staged fine
// scatter and coalesced csr write-out.
__launch_bounds__(256)
__global__ void binB_kernel(const unsigned* __restrict__ binned, const int* __restrict__ bbase,
                            int* __restrict__ rowptr, int* __restrict__ csr, int N) {
    __shared__ int cnt[512];           // degree count, then reused as fill
    __shared__ int chunk[256];
    __shared__ int excl[513];
    __shared__ int stag[SPANCAP];
    const int tid = threadIdx.x;
    const int b = blockIdx.x;
    const int node0 = b << BINBITS;
    if (node0 >= N) return;
    const int nn = min(512, N - node0);

    cnt[tid] = (tid < nn) ? 1 : 0;            // self-loop
    cnt[tid + 256] = (tid + 256 < nn) ? 1 : 0;
    __syncthreads();
    const int e0 = bbase[b], e1 = bbase[b + 1];
    for (int i = e0 + tid; i < e1; i += 256)
        atomicAdd(&cnt[binned[i] >> 17], 1);
    __syncthreads();

    // exclusive scan of 512 via 256 chunks of 2
    int c0v = cnt[2 * tid], c1v = cnt[2 * tid + 1];
    chunk[tid] = c0v + c1v;
    __syncthreads();
    int v = chunk[tid];
    for (int o = 1; o < 256; o <<= 1) {
        int x = (tid >= o) ? chunk[tid - o] : 0;
        __syncthreads();
        chunk[tid] += x;
        __syncthreads();
    }
    int cpre = chunk[tid] - v;                // exclusive chunk prefix
    excl[2 * tid] = cpre;
    excl[2 * tid + 1] = cpre + c0v;
    if (tid == 255) excl[512] = cpre + c0v + c1v;
    __syncthreads();

    const int rbase = e0 + node0;             // == rowptr[node0]
    for (int i = tid; i < nn; i += 256) rowptr[node0 + i] = rbase + excl[i];
    if (node0 + nn >= N && tid == 0) rowptr[N] = rbase + excl[512];

    // reuse cnt as fill
    cnt[tid] = 0;
    cnt[tid + 256] = 0;
    __syncthreads();
    const int span = excl[512];

    if (span <= SPANCAP) {
        for (int i = e0 + tid; i < e1; i += 256) {
            unsigned e = binned[i];
            int dloc = e >> 17, src = e & 0x1FFFF;
            int p = excl[dloc] + atomicAdd(&cnt[dloc], 1);
            stag[p] = src;
        }
        for (int i = tid; i < nn; i += 256) {   // self loops
            int p = excl[i] + atomicAdd(&cnt[i], 1);
            stag[p] = node0 + i;
        }
        __syncthreads();
        for (int i = tid; i < span; i += 256) csr[rbase + i] = stag[i];
    } else {                                    // pathological bucket: direct
        for (int i = e0 + tid; i < e1; i += 256) {
            unsigned e = binned[i];
            int dloc = e >> 17, src = e & 0x1FFFF;
            csr[rbase + excl[dloc] + atomicAdd(&cnt[dloc], 1)] = src;
        }
        for (int i = tid; i < nn; i += 256)
            csr[rbase + excl[i] + atomicAdd(&cnt[i], 1)] = node0 + i;
    }
}

// ------------------- GEMM (fp32) + fused attn epilogue -------------------
// 256 threads, BM = 128 rows, FOUT cols. Thread tile: TM rows x (4+4) cols,
// the two col-quads at tc*4 (head 0) and FOUT/2 + tc*4 (head 1).
// sX stored transposed [k][row] (pitch BM+4) so the TM-row slice is b128.

template <int FIN, int FOUT, int TM, int KC>
__launch_bounds__(256)
__global__ void gemm_attn_kernel(const float* __restrict__ X, const float* __restrict__ Wg,
                                 const float* __restrict__ atts, const float* __restrict__ attd,
                                 __half* __restrict__ Hh, float* __restrict__ a_s,
                                 float* __restrict__ a_d, int N) {
    constexpr int COLG = FOUT / 8;    // threads covering columns (16 / 8)
    constexpr int ROWG = 256 / COLG;  // threads covering rows (16 / 32)
    constexpr int BM = ROWG * TM;     // 128
    constexpr int C = FOUT / 2;       // head dim
    constexpr int PR = BM + 4;        // sX pitch (rows)
    __shared__ float sW[KC * FOUT];
    __shared__ float sX[KC * PR];

    const int tid = threadIdx.x;
    const int tc = tid % COLG;
    const int tr = tid / COLG;
    const int row0 = blockIdx.x * BM;

    float accA[TM][4], accB[TM][4];
#pragma unroll
    for (int i = 0; i < TM; ++i)
#pragma unroll
        for (int j = 0; j < 4; ++j) { accA[i][j] = 0.f; accB[i][j] = 0.f; }

    for (int kc = 0; kc < FIN; kc += KC) {
        __syncthreads();
        // stage W chunk: sW[k][c]
        for (int idx = tid; idx < KC * FOUT / 4; idx += 256) {
            int k = idx / (FOUT / 4), cq = idx % (FOUT / 4);
            *(float4*)&sW[k * FOUT + cq * 4] =
                *(const float4*)&Wg[(size_t)(kc + k) * FOUT + cq * 4];
        }
        // stage X chunk transposed: sX[k][r]
        for (int idx = tid; idx < BM * KC / 4; idx += 256) {
            int r = idx / (KC / 4), kq = idx % (KC / 4);
            int gr = row0 + r;
            float4 v = make_float4(0.f, 0.f, 0.f, 0.f);
            if (gr < N) v = *(const float4*)&X[(size_t)gr * FIN + kc + kq * 4];
            sX[(kq * 4 + 0) * PR + r] = v.x;
            sX[(kq * 4 + 1) * PR + r] = v.y;
            sX[(kq * 4 + 2) * PR + r] = v.z;
            sX[(kq * 4 + 3) * PR + r] = v.w;
        }
        __syncthreads();
#pragma unroll 4
        for (int k = 0; k < KC; ++k) {
            float xv[TM];
#pragma unroll
            for (int q = 0; q < TM / 4; ++q)
                *(float4*)&xv[q * 4] = *(const float4*)&sX[k * PR + tr * TM + q * 4];
            float wa[4], wb[4];
            *(float4*)wa = *(const float4*)&sW[k * FOUT + tc * 4];
            *(float4*)wb = *(const float4*)&sW[k * FOUT + C + tc * 4];
#pragma unroll
            for (int i = 0; i < TM; ++i) {
#pragma unroll
                for (int j = 0; j < 4; ++j) {
                    accA[i][j] = fmaf(xv[i], wa[j], accA[i][j]);
                    accB[i][j] = fmaf(xv[i], wb[j], accB[i][j]);
                }
            }
        }
    }

    // ---- epilogue: fp16 h store + attention scalars from fp32 acc ----
    float aSA[4], aSB[4], aDA[4], aDB[4];
#pragma unroll
    for (int j = 0; j < 4; ++j) {
        aSA[j] = atts[tc * 4 + j];        // head 0
        aSB[j] = atts[C + tc * 4 + j];    // head 1
        aDA[j] = attd[tc * 4 + j];
        aDB[j] = attd[C + tc * 4 + j];
    }

#pragma unroll
    for (int i = 0; i < TM; ++i) {
        int gr = row0 + tr * TM + i;
        if (gr < N) {
            union { int2 i2; __half2 h2[2]; } u;
            u.h2[0] = __halves2half2(__float2half(accA[i][0]), __float2half(accA[i][1]));
            u.h2[1] = __halves2half2(__float2half(accA[i][2]), __float2half(accA[i][3]));
            *reinterpret_cast<int2*>(&Hh[(size_t)gr * FOUT + tc * 4]) = u.i2;
            u.h2[0] = __halves2half2(__float2half(accB[i][0]), __float2half(accB[i][1]));
            u.h2[1] = __halves2half2(__float2half(accB[i][2]), __float2half(accB[i][3]));
            *reinterpret_cast<int2*>(&Hh[(size_t)gr * FOUT + C + tc * 4]) = u.i2;
        }
        float ps0 = 0.f, ps1 = 0.f, pd0 = 0.f, pd1 = 0.f;
#pragma unroll
        for (int j = 0; j < 4; ++j) {
            ps0 = fmaf(accA[i][j], aSA[j], ps0);
            ps1 = fmaf(accB[i][j], aSB[j], ps1);
            pd0 = fmaf(accA[i][j], aDA[j], pd0);
            pd1 = fmaf(accB[i][j], aDB[j], pd1);
        }
#pragma unroll
        for (int o = 1; o < COLG; o <<= 1) {
            ps0 += __shfl_xor(ps0, o);
            ps1 += __shfl_xor(ps1, o);
            pd0 += __shfl_xor(pd0, o);
            pd1 += __shfl_xor(pd1, o);
        }
        if (tc == 0 && gr < N) {
            *(float2*)&a_s[gr * 2] = make_float2(ps0, ps1);
            *(float2*)&a_d[gr * 2] = make_float2(pd0, pd1);
        }
    }
}

// --------------------- edge weights (normalized) ---------------------
// One wave per node. Pass 1: w_e = exp(lrelu(a_s[src]+a_d[n])) per head,
// written coalesced (unnormalized) + lane-partial denom. Then scale by
// 0.5/denom (head-mean folded in) with a coalesced read-modify-write.
// No max subtraction: logits are O(1), exp cannot overflow fp32.

__device__ __forceinline__ float lrelu02(float x) { return x > 0.f ? x : 0.2f * x; }

__launch_bounds__(256)
__global__ void edge_w_kernel(const float* __restrict__ a_s, const float* __restrict__ a_d,
                              const int* __restrict__ rowptr, const int* __restrict__ csr,
                              float2* __restrict__ w, int N) {
    const int wid = threadIdx.x >> 6, lane = threadIdx.x & 63;
    int n = blockIdx.x * 4 + wid;
    if (n >= N) return;
    int start = rowptr[n], end = rowptr[n + 1];
    float2 adn = ((const float2*)a_d)[n];
    float d0 = 0.f, d1 = 0.f;
    for (int j = start + lane; j < end; j += 64) {
        int s = csr[j];
        float2 asv = ((const float2*)a_s)[s];
        float e0 = __expf(lrelu02(asv.x + adn.x));
        float e1 = __expf(lrelu02(asv.y + adn.y));
        d0 += e0;
        d1 += e1;
        w[j] = make_float2(e0, e1);
    }
#pragma unroll
    for (int o = 32; o > 0; o >>= 1) {
        d0 += __shfl_xor(d0, o);
        d1 += __shfl_xor(d1, o);
    }
    float i0 = 0.5f / d0, i1 = 0.5f / d1;   // 0.5 = head mean
    for (int j = start + lane; j < end; j += 64) {
        float2 f = w[j];
        w[j] = make_float2(f.x * i0, f.y * i1);
    }
}

// ------------------------- gather aggregation (R7) -------------------------
// Pure weighted gather: one wave per node. Per 64-edge chunk, coalesced
// csr + w loads -> per-head (w, src) records in LDS; gather two edges per
// wave-instruction (lanes 0-31 even slots, 32-63 odd; within a half-wave
// sub 0-15 -> head 0, 16-31 -> head 1; 4ch/lane ushort4 at C=64, 2ch/lane
// half2 at C=32). Weights arrive pre-normalized (0.5/denom folded in), so
// the tail is: shfl 32 (edge subsets) + shfl 16 (head sum) + bias + act.

template <int C, bool ELU>
__launch_bounds__(256)
__global__ void aggregate_kernel(const __half* __restrict__ Hh, const float2* __restrict__ w,
                                 const int* __restrict__ rowptr, const int* __restrict__ csr,
                                 const float* __restrict__ bias, float* __restrict__ out, int N) {
    __shared__ float2 swH[4][64][2];   // [wave][slot][head] = (w, src-bits)
    const int wid = threadIdx.x >> 6;
    const int lane = threadIdx.x & 63;
    const int hp = lane >> 5;          // which edge of a slot-pair
    const int sub = lane & 31;
    const int head = sub >> 4;
    const int chq = sub & 15;          // channel quad (C=64) / pair (C=32)
    int n = blockIdx.x * 4 + wid;
    if (n >= N) return;
    int start = rowptr[n], end = rowptr[n + 1];

    float acc0 = 0.f, acc1 = 0.f, acc2 = 0.f, acc3 = 0.f;

    for (int cs = start; cs < end; cs += 64) {
        int j = cs + lane;
        float2 wv = make_float2(0.f, 0.f);
        int s = 0;
        if (j < end) {
            s = csr[j];
            wv = w[j];
        }
        float fs = __int_as_float(s);
        swH[wid][lane][0] = make_float2(wv.x, fs);
        swH[wid][lane][1] = make_float2(wv.y, fs);
        int cnt = min(64, end - cs);
        int npair = (cnt + 1) >> 1;    // <= 32; slot 2p+hp <= 63 always
        for (int p0 = 0; p0 < npair; p0 += 4) {
            float2 e[4];
#pragma unroll
            for (int u = 0; u < 4; ++u)
                e[u] = swH[wid][2 * (p0 + u) + hp][head];  // padded slots: w=0
            if (C == 64) {
                ushort4 hv[4];
#pragma unroll
                for (int u = 0; u < 4; ++u)
                    hv[u] = ((const ushort4*)Hh)[(size_t)__float_as_int(e[u].y) * 32 + sub];
#pragma unroll
                for (int u = 0; u < 4; ++u) {
                    const __half* hx = (const __half*)&hv[u];
                    acc0 = fmaf(e[u].x, __half2float(hx[0]), acc0);
                    acc1 = fmaf(e[u].x, __half2float(hx[1]), acc1);
                    acc2 = fmaf(e[u].x, __half2float(hx[2]), acc2);
                    acc3 = fmaf(e[u].x, __half2float(hx[3]), acc3);
                }
            } else {
                __half2 hv[4];
#pragma unroll
                for (int u = 0; u < 4; ++u)
                    hv[u] = ((const __half2*)Hh)[(size_t)__float_as_int(e[u].y) * 32 + sub];
#pragma unroll
                for (int u = 0; u < 4; ++u) {
                    float2 v = __half22float2(hv[u]);
                    acc0 = fmaf(e[u].x, v.x, acc0);
                    acc1 = fmaf(e[u].x, v.y, acc1);
                }
            }
        }
    }

    // merge the two edge subsets (even/odd slots)
    acc0 += __shfl_xor(acc0, 32);
    acc1 += __shfl_xor(acc1, 32);
    if (C == 64) {
        acc2 += __shfl_xor(acc2, 32);
        acc3 += __shfl_xor(acc3, 32);
    }
    // head mean (0.5/denom already folded into w): sub s + sub s+16
    acc0 += __shfl_xor(acc0, 16);
    acc1 += __shfl_xor(acc1, 16);
    if (C == 64) {
        acc2 += __shfl_xor(acc2, 16);
        acc3 += __shfl_xor(acc3, 16);
    }

    if (lane < 16) {
        if (C == 64) {
            float4 bv = *(const float4*)(bias + chq * 4);
            float o0 = acc0 + bv.x;
            float o1 = acc1 + bv.y;
            float o2 = acc2 + bv.z;
            float o3 = acc3 + bv.w;
            if (ELU) {
                o0 = o0 > 0.f ? o0 : expm1f(o0);
                o1 = o1 > 0.f ? o1 : expm1f(o1);
                o2 = o2 > 0.f ? o2 : expm1f(o2);
                o3 = o3 > 0.f ? o3 : expm1f(o3);
            }
            *(float4*)(out + (size_t)n * 64 + chq * 4) = make_float4(o0, o1, o2, o3);
        } else {
            float2 bv = *(const float2*)(bias + chq * 2);
            float o0 = acc0 + bv.x;
            float o1 = acc1 + bv.y;
            if (ELU) {
                o0 = o0 > 0.f ? o0 : expm1f(o0);
                o1 = o1 > 0.f ? o1 : expm1f(o1);
            }
            *(float2*)(out + (size_t)n * 32 + chq * 2) = make_float2(o0, o1);
        }
    }
}

// ------------------------- launch -------------------------

extern "C" void kernel_launch(void* const* d_in, const int* in_sizes, int n_in,
                              void* d_out, int out_size, void* d_ws, size_t ws_size,
                              hipStream_t stream) {
    const float* x    = (const float*)d_in[0];
    const int*   eidx = (const int*)d_in[1];
    const float* W1   = (const float*)d_in[2];
    const float* as1w = (const float*)d_in[3];
    const float* ad1w = (const float*)d_in[4];
    const float* b1   = (const float*)d_in[5];
    const float* W2   = (const float*)d_in[6];
    const float* as2w = (const float*)d_in[7];
    const float* ad2w = (const float*)d_in[8];
    const float* b2   = (const float*)d_in[9];
    float* out = (float*)d_out;

    const int N = in_sizes[0] / 128;  // Fin = 128
    const int E = in_sizes[1] / 2;
    const int NBK = (N + (1 << BINBITS) - 1) >> BINBITS;

    char* base = (char*)d_ws;
    size_t off = 0;
    auto alloc = [&](size_t bytes) {
        size_t cur = off;
        off += (bytes + 255) & ~(size_t)255;
        return (void*)(base + cur);
    };

    int* rowptr   = (int*)alloc((size_t)(N + 1) * 4);
    int* csr      = (int*)alloc((size_t)(E + N) * 4);
    int* bcnt     = (int*)alloc((size_t)NBUCK * 4);
    int* bbase    = (int*)alloc((size_t)(NBUCK + 1) * 4);
    int* bfill    = (int*)alloc((size_t)NBUCK * 4);
    unsigned* binned = (unsigned*)alloc((size_t)E * 4);
    __half* h1    = (__half*)alloc((size_t)N * 128 * 2);  // fp16, reused as h2
    float* x2     = (float*)alloc((size_t)N * 64 * 4);
    float* a_s    = (float*)alloc((size_t)N * 2 * 4);
    float* a_d    = (float*)alloc((size_t)N * 2 * 4);
    float2* wEdge = (float2*)alloc((size_t)(E + N) * 8);

    const int* esrc = eidx;
    const int* edst = eidx + E;

    // --- CSR build (shared by both layers) ---
    init_kernel<<<1, NBUCK, 0, stream>>>(bcnt);
    bucket_hist_kernel<<<256, 256, 0, stream>>>(edst, bcnt, E);
    bucket_scan_kernel<<<1, NBUCK, 0, stream>>>(bcnt, bbase, bfill);
    binA_kernel<<<(E + CHUNK - 1) / CHUNK, 256, 0, stream>>>(esrc, edst, bfill, binned, E);
    binB_kernel<<<NBK, 256, 0, stream>>>(binned, bbase, rowptr, csr, N);

    // --- Layer 1 (Fin=128 -> H=2, C=64) ---
    gemm_attn_kernel<128, 128, 8, 32>
        <<<(N + 127) / 128, 256, 0, stream>>>(x, W1, as1w, ad1w, h1, a_s, a_d, N);
    edge_w_kernel<<<(N + 3) / 4, 256, 0, stream>>>(a_s, a_d, rowptr, csr, wEdge, N);
    aggregate_kernel<64, true><<<(N + 3) / 4, 256, 0, stream>>>(h1, wEdge, rowptr, csr, b1, x2, N);

    // --- Layer 2 (Fin=64 -> H=2, C=32) ---
    gemm_attn_kernel<64, 64, 4, 32>
        <<<(N + 127) / 128, 256, 0, stream>>>(x2, W2, as2w, ad2w, h1, a_s, a_d, N);
    edge_w_kernel<<<(N + 3) / 4, 256, 0, stream>>>(a_s, a_d, rowptr, csr, wEdge, N);
    aggregate_kernel<32, false><<<(N + 3) / 4, 256, 0, stream>>>(h1, wEdge, rowptr, csr, b2, out, N);
}

// Round 8
// 374.570 us; speedup vs baseline: 2.2472x; 1.0597x over previous
//
#include <hip/hip_runtime.h>
#include <hip/hip_bf16.h>
#include <hip/hip_fp16.h>
#include <math.h>

// ---------------------------------------------------------------------------
// GAT 2-layer forward.
// R8: GEMMs moved to fp16 MFMA (16x16x32_f16, fp32 acc). W pre-converted to
//     transposed fp16 (wcvt); whole-K LDS tiles, one staging barrier; attn
//     logits from fp32 accumulators; h stored fp16 via LDS-coalesced stores;
//     aggregate1 emits fp16 x2 so gemm2 stages A by b128 copy.
// Pipeline: CSR build (bucketed, R7) -> gemm_attn_mfma -> edge_w -> aggregate.
// ---------------------------------------------------------------------------

#define BINBITS 9                 // nodes per bucket = 512
#define NBUCK 256                 // covers N < 131072
#define CHUNK 4096                // edges per WG in binA
#define SPANCAP 12288             // LDS staging capacity in binB (ints)

typedef _Float16 half8 __attribute__((ext_vector_type(8)));
typedef float f32x4 __attribute__((ext_vector_type(4)));

// ------------------------- CSR build -------------------------

__global__ void init_kernel(int* __restrict__ bcnt) {
    bcnt[threadIdx.x] = 0;
}

__global__ void bucket_hist_kernel(const int* __restrict__ dst, int* __restrict__ bcnt, int E) {
    __shared__ int h[NBUCK];
    int t = threadIdx.x;
    h[t] = 0;
    __syncthreads();
    for (int i = blockIdx.x * blockDim.x + t; i < E; i += gridDim.x * blockDim.x)
        atomicAdd(&h[dst[i] >> BINBITS], 1);
    __syncthreads();
    if (h[t]) atomicAdd(&bcnt[t], h[t]);
}

__global__ void bucket_scan_kernel(const int* __restrict__ bcnt, int* __restrict__ bbase,
                                   int* __restrict__ bfill) {
    __shared__ int sd[NBUCK];
    int t = threadIdx.x;
    int v = bcnt[t];
    sd[t] = v;
    __syncthreads();
    for (int o = 1; o < NBUCK; o <<= 1) {
        int x = (t >= o) ? sd[t - o] : 0;
        __syncthreads();
        sd[t] += x;
        __syncthreads();
    }
    int exc = sd[t] - v;
    bbase[t] = exc;
    bfill[t] = exc;
    if (t == NBUCK - 1) bbase[NBUCK] = sd[t];  // = E
}

__launch_bounds__(256)
__global__ void binA_kernel(const int* __restrict__ esrc, const int* __restrict__ edst,
                            int* __restrict__ bfill, unsigned* __restrict__ binned, int E) {
    __shared__ unsigned stage[CHUNK];
    __shared__ int hcnt[NBUCK], hexc[NBUCK], gb[NBUCK], hfill[NBUCK];
    const int tid = threadIdx.x;
    const int c0 = blockIdx.x * CHUNK;
    const int n = min(CHUNK, E - c0);

    hcnt[tid] = 0;
    hfill[tid] = 0;
    __syncthreads();
    for (int i = tid; i < n; i += 256) atomicAdd(&hcnt[edst[c0 + i] >> BINBITS], 1);
    __syncthreads();
    int myc = hcnt[tid];
    hexc[tid] = myc;
    __syncthreads();
    for (int o = 1; o < NBUCK; o <<= 1) {       // inclusive scan
        int x = (tid >= o) ? hexc[tid - o] : 0;
        __syncthreads();
        hexc[tid] += x;
        __syncthreads();
    }
    hexc[tid] -= myc;                           // exclusive
    gb[tid] = myc ? atomicAdd(&bfill[tid], myc) : 0;
    __syncthreads();

    for (int i = tid; i < n; i += 256) {
        int d = edst[c0 + i], s = esrc[c0 + i];
        int b = d >> BINBITS;
        int p = hexc[b] + atomicAdd(&hfill[b], 1);
        stage[p] = ((unsigned)(d & ((1 << BINBITS) - 1)) << 17) | (unsigned)s;
    }
    __syncthreads();

    const int wid = tid >> 6, lane = tid & 63;
    for (int b = wid * 64; b < wid * 64 + 64; ++b) {
        int cnt = hcnt[b], sb = hexc[b], g = gb[b];
        for (int l = lane; l < cnt; l += 64) binned[g + l] = stage[sb + l];
    }
}

// binB: per-bucket local rowptr derivation + LDS-staged fine scatter.
__launch_bounds__(256)
__global__ void binB_kernel(const unsigned* __restrict__ binned, const int* __restrict__ bbase,
                            int* __restrict__ rowptr, int* __restrict__ csr, int N) {
    __shared__ int cnt[512];           // degree count, then reused as fill
    __shared__ int chunk[256];
    __shared__ int excl[513];
    __shared__ int stag[SPANCAP];
    const int tid = threadIdx.x;
    const int b = blockIdx.x;
    const int node0 = b << BINBITS;
    if (node0 >= N) return;
    const int nn = min(512, N - node0);

    cnt[tid] = (tid < nn) ? 1 : 0;            // self-loop
    cnt[tid + 256] = (tid + 256 < nn) ? 1 : 0;
    __syncthreads();
    const int e0 = bbase[b], e1 = bbase[b + 1];
    for (int i = e0 + tid; i < e1; i += 256)
        atomicAdd(&cnt[binned[i] >> 17], 1);
    __syncthreads();

    int c0v = cnt[2 * tid], c1v = cnt[2 * tid + 1];
    chunk[tid] = c0v + c1v;
    __syncthreads();
    int v = chunk[tid];
    for (int o = 1; o < 256; o <<= 1) {
        int x = (tid >= o) ? chunk[tid - o] : 0;
        __syncthreads();
        chunk[tid] += x;
        __syncthreads();
    }
    int cpre = chunk[tid] - v;                // exclusive chunk prefix
    excl[2 * tid] = cpre;
    excl[2 * tid + 1] = cpre + c0v;
    if (tid == 255) excl[512] = cpre + c0v + c1v;
    __syncthreads();

    const int rbase = e0 + node0;             // == rowptr[node0]
    for (int i = tid; i < nn; i += 256) rowptr[node0 + i] = rbase + excl[i];
    if (node0 + nn >= N && tid == 0) rowptr[N] = rbase + excl[512];

    cnt[tid] = 0;
    cnt[tid + 256] = 0;
    __syncthreads();
    const int span = excl[512];

    if (span <= SPANCAP) {
        for (int i = e0 + tid; i < e1; i += 256) {
            unsigned e = binned[i];
            int dloc = e >> 17, src = e & 0x1FFFF;
            int p = excl[dloc] + atomicAdd(&cnt[dloc], 1);
            stag[p] = src;
        }
        for (int i = tid; i < nn; i += 256) {
            int p = excl[i] + atomicAdd(&cnt[i], 1);
            stag[p] = node0 + i;
        }
        __syncthreads();
        for (int i = tid; i < span; i += 256) csr[rbase + i] = stag[i];
    } else {
        for (int i = e0 + tid; i < e1; i += 256) {
            unsigned e = binned[i];
            int dloc = e >> 17, src = e & 0x1FFFF;
            csr[rbase + excl[dloc] + atomicAdd(&cnt[dloc], 1)] = src;
        }
        for (int i = tid; i < nn; i += 256)
            csr[rbase + excl[i] + atomicAdd(&cnt[i], 1)] = node0 + i;
    }
}

// ------------------- W -> fp16 transposed (per call) -------------------
// Wt[n][k] = (fp16) W[k][n]; consumed as MFMA B-fragments (contiguous k).

__global__ void wcvt_kernel(const float* __restrict__ W, _Float16* __restrict__ Wt,
                            int K, int Fout) {
    int i = blockIdx.x * 256 + threadIdx.x;
    if (i < K * Fout) {
        int n = i / K, k = i % K;
        Wt[i] = (_Float16)W[k * Fout + n];
    }
}

// ------------------- MFMA GEMM (fp16 in, fp32 acc) + attn epilogue -------
// 256 threads = 4 waves; block tile BM=128 rows x FOUT cols, whole K in LDS.
// Wave w: rows [32w, 32w+32) as 2 m-tiles x NT n-tiles of mfma 16x16x32_f16.
// Layouts (verified, cdna_hip_programming §3/m120):
//   A[m=lane&15][k=quad*8+j]  B[k=quad*8+j][n=lane&15]
//   C/D: col=lane&15, row=quad*4+reg
// Epilogue: attn scalars from fp32 acc (quad shuffle reduce); h -> fp16 via
// LDS transpose (reuses sA) then coalesced b128 global stores.

template <int FIN, int FOUT, typename XT>
__launch_bounds__(256)
__global__ void gemm_attn_mfma(const XT* __restrict__ X, const _Float16* __restrict__ Wt,
                               const float* __restrict__ atts, const float* __restrict__ attd,
                               __half* __restrict__ Hh, float* __restrict__ a_s,
                               float* __restrict__ a_d, int N) {
    constexpr int BM = 128;
    constexpr int C = FOUT / 2;
    constexpr int NT = FOUT / 16;     // n-tiles per wave (8 / 4)
    constexpr int KS = FIN / 32;      // k-steps (4 / 2)
    constexpr int HT = C / 16;        // n-tiles per head
    __shared__ _Float16 sA[BM * FIN];
    __shared__ _Float16 sB[FOUT * FIN];

    const int tid = threadIdx.x;
    const int wv = tid >> 6, ln = tid & 63;
    const int lm = ln & 15, quad = ln >> 4;
    const int row0 = blockIdx.x * BM;

    // ---- stage A (rows, k contiguous) ----
    if (sizeof(XT) == 4) {
        for (int idx = tid; idx < BM * FIN / 4; idx += 256) {
            int r = idx / (FIN / 4), c4 = idx % (FIN / 4);
            int gr = row0 + r;
            float4 v = make_float4(0.f, 0.f, 0.f, 0.f);
            if (gr < N) v = *(const float4*)&((const float*)X)[(size_t)gr * FIN + c4 * 4];
            _Float16 h4[4] = {(_Float16)v.x, (_Float16)v.y, (_Float16)v.z, (_Float16)v.w};
            *(float2*)&sA[r * FIN + c4 * 4] = *(float2*)h4;
        }
    } else {
        for (int idx = tid; idx < BM * FIN / 8; idx += 256) {
            int r = idx / (FIN / 8), c8 = idx % (FIN / 8);
            int gr = row0 + r;
            int4 v = make_int4(0, 0, 0, 0);
            if (gr < N) v = *(const int4*)&((const __half*)X)[(size_t)gr * FIN + c8 * 8];
            *(int4*)&sA[r * FIN + c8 * 8] = v;
        }
    }
    // ---- stage B (Wt contiguous copy) ----
    for (int idx = tid; idx < FOUT * FIN / 8; idx += 256)
        *(int4*)&sB[idx * 8] = *(const int4*)&Wt[idx * 8];
    __syncthreads();

    // ---- MFMA K-loop ----
    f32x4 acc[2][NT];
#pragma unroll
    for (int mt = 0; mt < 2; ++mt)
#pragma unroll
        for (int nt = 0; nt < NT; ++nt) acc[mt][nt] = f32x4{0.f, 0.f, 0.f, 0.f};

    const int r0 = wv * 32 + lm;
#pragma unroll
    for (int ks = 0; ks < KS; ++ks) {
        int k0 = ks * 32 + quad * 8;
        half8 a0 = *(const half8*)&sA[r0 * FIN + k0];
        half8 a1 = *(const half8*)&sA[(r0 + 16) * FIN + k0];
#pragma unroll
        for (int nt = 0; nt < NT; ++nt) {
            half8 b = *(const half8*)&sB[(nt * 16 + lm) * FIN + k0];
            acc[0][nt] = __builtin_amdgcn_mfma_f32_16x16x32_f16(a0, b, acc[0][nt], 0, 0, 0);
            acc[1][nt] = __builtin_amdgcn_mfma_f32_16x16x32_f16(a1, b, acc[1][nt], 0, 0, 0);
        }
    }

    // ---- attn scalars from fp32 acc ----
    float psum[2][4][2], pdum[2][4][2];  // [mt][reg][head]
#pragma unroll
    for (int mt = 0; mt < 2; ++mt)
#pragma unroll
        for (int r = 0; r < 4; ++r) {
            psum[mt][r][0] = psum[mt][r][1] = 0.f;
            pdum[mt][r][0] = pdum[mt][r][1] = 0.f;
        }
#pragma unroll
    for (int nt = 0; nt < NT; ++nt) {
        float av = atts[nt * 16 + lm];
        float dv = attd[nt * 16 + lm];
        int hh = nt / HT;
#pragma unroll
        for (int mt = 0; mt < 2; ++mt)
#pragma unroll
            for (int r = 0; r < 4; ++r) {
                psum[mt][r][hh] = fmaf(acc[mt][nt][r], av, psum[mt][r][hh]);
                pdum[mt][r][hh] = fmaf(acc[mt][nt][r], dv, pdum[mt][r][hh]);
            }
    }
#pragma unroll
    for (int o = 1; o < 16; o <<= 1) {
#pragma unroll
        for (int mt = 0; mt < 2; ++mt)
#pragma unroll
            for (int r = 0; r < 4; ++r) {
                psum[mt][r][0] += __shfl_xor(psum[mt][r][0], o);
                psum[mt][r][1] += __shfl_xor(psum[mt][r][1], o);
                pdum[mt][r][0] += __shfl_xor(pdum[mt][r][0], o);
                pdum[mt][r][1] += __shfl_xor(pdum[mt][r][1], o);
            }
    }
    if (lm == 0) {
#pragma unroll
        for (int mt = 0; mt < 2; ++mt)
#pragma unroll
            for (int r = 0; r < 4; ++r) {
                int gr = row0 + wv * 32 + mt * 16 + quad * 4 + r;
                if (gr < N) {
                    *(float2*)&a_s[gr * 2] = make_float2(psum[mt][r][0], psum[mt][r][1]);
                    *(float2*)&a_d[gr * 2] = make_float2(pdum[mt][r][0], pdum[mt][r][1]);
                }
            }
    }

    // ---- h -> fp16 via LDS transpose (reuse sA), coalesced store ----
    __syncthreads();
    _Float16* sH = sA;  // BM*FOUT <= BM*FIN
#pragma unroll
    for (int mt = 0; mt < 2; ++mt)
#pragma unroll
        for (int nt = 0; nt < NT; ++nt)
#pragma unroll
            for (int r = 0; r < 4; ++r)
                sH[(wv * 32 + mt * 16 + quad * 4 + r) * FOUT + nt * 16 + lm] =
                    (_Float16)acc[mt][nt][r];
    __syncthreads();
    for (int idx = tid; idx < BM * FOUT / 8; idx += 256) {
        int r = idx / (FOUT / 8), c8 = idx % (FOUT / 8);
        int gr = row0 + r;
        if (gr < N)
            *(int4*)&Hh[(size_t)gr * FOUT + c8 * 8] = *(const int4*)&sH[r * FOUT + c8 * 8];
    }
}

// --------------------- edge weights (normalized) ---------------------

__device__ __forceinline__ float lrelu02(float x) { return x > 0.f ? x : 0.2f * x; }

__launch_bounds__(256)
__global__ void edge_w_kernel(const float* __restrict__ a_s, const float* __restrict__ a_d,
                              const int* __restrict__ rowptr, const int* __restrict__ csr,
                              float2* __restrict__ w, int N) {
    const int wid = threadIdx.x >> 6, lane = threadIdx.x & 63;
    int n = blockIdx.x * 4 + wid;
    if (n >= N) return;
    int start = rowptr[n], end = rowptr[n + 1];
    float2 adn = ((const float2*)a_d)[n];
    float d0 = 0.f, d1 = 0.f;
    for (int j = start + lane; j < end; j += 64) {
        int s = csr[j];
        float2 asv = ((const float2*)a_s)[s];
        float e0 = __expf(lrelu02(asv.x + adn.x));
        float e1 = __expf(lrelu02(asv.y + adn.y));
        d0 += e0;
        d1 += e1;
        w[j] = make_float2(e0, e1);
    }
#pragma unroll
    for (int o = 32; o > 0; o >>= 1) {
        d0 += __shfl_xor(d0, o);
        d1 += __shfl_xor(d1, o);
    }
    float i0 = 0.5f / d0, i1 = 0.5f / d1;   // 0.5 = head mean
    for (int j = start + lane; j < end; j += 64) {
        float2 f = w[j];
        w[j] = make_float2(f.x * i0, f.y * i1);
    }
}

// ------------------------- gather aggregation -------------------------
// Pure weighted gather (R7 structure); OT selects fp16 (x2) or fp32 (out).

template <int C, bool ELU, typename OT>
__launch_bounds__(256)
__global__ void aggregate_kernel(const __half* __restrict__ Hh, const float2* __restrict__ w,
                                 const int* __restrict__ rowptr, const int* __restrict__ csr,
                                 const float* __restrict__ bias, OT* __restrict__ out, int N) {
    __shared__ float2 swH[4][64][2];   // [wave][slot][head] = (w, src-bits)
    const int wid = threadIdx.x >> 6;
    const int lane = threadIdx.x & 63;
    const int hp = lane >> 5;          // which edge of a slot-pair
    const int sub = lane & 31;
    const int head = sub >> 4;
    const int chq = sub & 15;          // channel quad (C=64) / pair (C=32)
    int n = blockIdx.x * 4 + wid;
    if (n >= N) return;
    int start = rowptr[n], end = rowptr[n + 1];

    float acc0 = 0.f, acc1 = 0.f, acc2 = 0.f, acc3 = 0.f;

    for (int cs = start; cs < end; cs += 64) {
        int j = cs + lane;
        float2 wv = make_float2(0.f, 0.f);
        int s = 0;
        if (j < end) {
            s = csr[j];
            wv = w[j];
        }
        float fs = __int_as_float(s);
        swH[wid][lane][0] = make_float2(wv.x, fs);
        swH[wid][lane][1] = make_float2(wv.y, fs);
        int cnt = min(64, end - cs);
        int npair = (cnt + 1) >> 1;    // <= 32; slot 2p+hp <= 63 always
        for (int p0 = 0; p0 < npair; p0 += 4) {
            float2 e[4];
#pragma unroll
            for (int u = 0; u < 4; ++u)
                e[u] = swH[wid][2 * (p0 + u) + hp][head];  // padded slots: w=0
            if (C == 64) {
                ushort4 hv[4];
#pragma unroll
                for (int u = 0; u < 4; ++u)
                    hv[u] = ((const ushort4*)Hh)[(size_t)__float_as_int(e[u].y) * 32 + sub];
#pragma unroll
                for (int u = 0; u < 4; ++u) {
                    const __half* hx = (const __half*)&hv[u];
                    acc0 = fmaf(e[u].x, __half2float(hx[0]), acc0);
                    acc1 = fmaf(e[u].x, __half2float(hx[1]), acc1);
                    acc2 = fmaf(e[u].x, __half2float(hx[2]), acc2);
                    acc3 = fmaf(e[u].x, __half2float(hx[3]), acc3);
                }
            } else {
                __half2 hv[4];
#pragma unroll
                for (int u = 0; u < 4; ++u)
                    hv[u] = ((const __half2*)Hh)[(size_t)__float_as_int(e[u].y) * 32 + sub];
#pragma unroll
                for (int u = 0; u < 4; ++u) {
                    float2 v = __half22float2(hv[u]);
                    acc0 = fmaf(e[u].x, v.x, acc0);
                    acc1 = fmaf(e[u].x, v.y, acc1);
                }
            }
        }
    }

    // merge even/odd edge subsets, then heads (0.5/denom folded into w)
    acc0 += __shfl_xor(acc0, 32);
    acc1 += __shfl_xor(acc1, 32);
    if (C == 64) {
        acc2 += __shfl_xor(acc2, 32);
        acc3 += __shfl_xor(acc3, 32);
    }
    acc0 += __shfl_xor(acc0, 16);
    acc1 += __shfl_xor(acc1, 16);
    if (C == 64) {
        acc2 += __shfl_xor(acc2, 16);
        acc3 += __shfl_xor(acc3, 16);
    }

    if (lane < 16) {
        if (C == 64) {
            float4 bv = *(const float4*)(bias + chq * 4);
            float o0 = acc0 + bv.x;
            float o1 = acc1 + bv.y;
            float o2 = acc2 + bv.z;
            float o3 = acc3 + bv.w;
            if (ELU) {
                o0 = o0 > 0.f ? o0 : expm1f(o0);
                o1 = o1 > 0.f ? o1 : expm1f(o1);
                o2 = o2 > 0.f ? o2 : expm1f(o2);
                o3 = o3 > 0.f ? o3 : expm1f(o3);
            }
            if (sizeof(OT) == 2) {
                __half2 p0 = __floats2half2_rn(o0, o1);
                __half2 p1 = __floats2half2_rn(o2, o3);
                ((__half2*)out)[(size_t)n * 32 + chq * 2] = p0;
                ((__half2*)out)[(size_t)n * 32 + chq * 2 + 1] = p1;
            } else {
                *(float4*)((float*)out + (size_t)n * 64 + chq * 4) =
                    make_float4(o0, o1, o2, o3);
            }
        } else {
            float2 bv = *(const float2*)(bias + chq * 2);
            float o0 = acc0 + bv.x;
            float o1 = acc1 + bv.y;
            if (ELU) {
                o0 = o0 > 0.f ? o0 : expm1f(o0);
                o1 = o1 > 0.f ? o1 : expm1f(o1);
            }
            *(float2*)((float*)out + (size_t)n * 32 + chq * 2) = make_float2(o0, o1);
        }
    }
}

// ------------------------- launch -------------------------

extern "C" void kernel_launch(void* const* d_in, const int* in_sizes, int n_in,
                              void* d_out, int out_size, void* d_ws, size_t ws_size,
                              hipStream_t stream) {
    const float* x    = (const float*)d_in[0];
    const int*   eidx = (const int*)d_in[1];
    const float* W1   = (const float*)d_in[2];
    const float* as1w = (const float*)d_in[3];
    const float* ad1w = (const float*)d_in[4];
    const float* b1   = (const float*)d_in[5];
    const float* W2   = (const float*)d_in[6];
    const float* as2w = (const float*)d_in[7];
    const float* ad2w = (const float*)d_in[8];
    const float* b2   = (const float*)d_in[9];
    float* out = (float*)d_out;

    const int N = in_sizes[0] / 128;  // Fin = 128
    const int E = in_sizes[1] / 2;
    const int NBK = (N + (1 << BINBITS) - 1) >> BINBITS;

    char* base = (char*)d_ws;
    size_t off = 0;
    auto alloc = [&](size_t bytes) {
        size_t cur = off;
        off += (bytes + 255) & ~(size_t)255;
        return (void*)(base + cur);
    };

    int* rowptr   = (int*)alloc((size_t)(N + 1) * 4);
    int* csr      = (int*)alloc((size_t)(E + N) * 4);
    int* bcnt     = (int*)alloc((size_t)NBUCK * 4);
    int* bbase    = (int*)alloc((size_t)(NBUCK + 1) * 4);
    int* bfill    = (int*)alloc((size_t)NBUCK * 4);
    unsigned* binned = (unsigned*)alloc((size_t)E * 4);
    __half* h1    = (__half*)alloc((size_t)N * 128 * 2);  // fp16, reused as h2
    __half* x2h   = (__half*)alloc((size_t)N * 64 * 2);   // fp16 layer-2 input
    float* a_s    = (float*)alloc((size_t)N * 2 * 4);
    float* a_d    = (float*)alloc((size_t)N * 2 * 4);
    float2* wEdge = (float2*)alloc((size_t)(E + N) * 8);
    _Float16* Wt1 = (_Float16*)alloc((size_t)128 * 128 * 2);
    _Float16* Wt2 = (_Float16*)alloc((size_t)64 * 64 * 2);

    const int* esrc = eidx;
    const int* edst = eidx + E;

    // --- CSR build (shared by both layers) ---
    init_kernel<<<1, NBUCK, 0, stream>>>(bcnt);
    bucket_hist_kernel<<<256, 256, 0, stream>>>(edst, bcnt, E);
    bucket_scan_kernel<<<1, NBUCK, 0, stream>>>(bcnt, bbase, bfill);
    binA_kernel<<<(E + CHUNK - 1) / CHUNK, 256, 0, stream>>>(esrc, edst, bfill, binned, E);
    binB_kernel<<<NBK, 256, 0, stream>>>(binned, bbase, rowptr, csr, N);

    // --- weight conversion (fp16, transposed) ---
    wcvt_kernel<<<(128 * 128 + 255) / 256, 256, 0, stream>>>(W1, Wt1, 128, 128);
    wcvt_kernel<<<(64 * 64 + 255) / 256, 256, 0, stream>>>(W2, Wt2, 64, 64);

    // --- Layer 1 (Fin=128 -> H=2, C=64) ---
    gemm_attn_mfma<128, 128, float>
        <<<(N + 127) / 128, 256, 0, stream>>>(x, Wt1, as1w, ad1w, h1, a_s, a_d, N);
    edge_w_kernel<<<(N + 3) / 4, 256, 0, stream>>>(a_s, a_d, rowptr, csr, wEdge, N);
    aggregate_kernel<64, true, __half>
        <<<(N + 3) / 4, 256, 0, stream>>>(h1, wEdge, rowptr, csr, b1, x2h, N);

    // --- Layer 2 (Fin=64 -> H=2, C=32) ---
    gemm_attn_mfma<64, 64, __half>
        <<<(N + 127) / 128, 256, 0, stream>>>(x2h, Wt2, as2w, ad2w, h1, a_s, a_d, N);
    edge_w_kernel<<<(N + 3) / 4, 256, 0, stream>>>(a_s, a_d, rowptr, csr, wEdge, N);
    aggregate_kernel<32, false, float>
        <<<(N + 3) / 4, 256, 0, stream>>>(h1, wEdge, rowptr, csr, b2, out, N);
}